// Round 1
// baseline (1649.559 us; speedup 1.0000x reference)
//
#include <hip/hip_runtime.h>
#include <hip/hip_bf16.h>
#include <math.h>

typedef __bf16  bf16x8 __attribute__((ext_vector_type(8)));
typedef float   f32x4  __attribute__((ext_vector_type(4)));

#define MFMA16(a,b,c) __builtin_amdgcn_mfma_f32_16x16x32_bf16((a),(b),(c),0,0,0)

__device__ __forceinline__ bf16x8 cvt8(const float* p) {
  const f32x4* q = (const f32x4*)p;
  f32x4 u = q[0], v = q[1];
  bf16x8 r;
  r[0]=(__bf16)u[0]; r[1]=(__bf16)u[1]; r[2]=(__bf16)u[2]; r[3]=(__bf16)u[3];
  r[4]=(__bf16)v[0]; r[5]=(__bf16)v[1]; r[6]=(__bf16)v[2]; r[7]=(__bf16)v[3];
  return r;
}

__device__ __forceinline__ float sigf(float x){ return 1.0f/(1.0f + __expf(-x)); }

// ---------------- weight prep ----------------
// M[i][r][c] = sum_j Whh[i][r][j] * fe_w2[i][j][c]  (bf16 out)
// wb[i][r]   = sum_j Whh[i][r][j] * fe_b2[i][j]
__global__ __launch_bounds__(256) void k_prep_M(const float* __restrict__ whh,
                                                const float* __restrict__ w2,
                                                const float* __restrict__ b2,
                                                __bf16* __restrict__ Mout,
                                                float* __restrict__ wb, int P_) {
  int idx = blockIdx.x*blockDim.x + threadIdx.x;
  if (idx >= P_*256*64) return;
  int c = idx & 63; int r = (idx >> 6) & 255; int i = idx >> 14;
  const float* wh  = whh + ((size_t)i*256 + r)*64;
  const float* w2i = w2  + (size_t)i*64*64;
  float acc = 0.f;
  #pragma unroll 8
  for (int j=0;j<64;j++) acc += wh[j] * w2i[j*64 + c];
  Mout[idx] = (__bf16)acc;
  if (c == 0) {
    const float* b2i = b2 + i*64;
    float a2 = 0.f;
    for (int j=0;j<64;j++) a2 += wh[j]*b2i[j];
    wb[i*256 + r] = a2;
  }
}

// convert fe_w1 splits / lstm_wih / readout weights to bf16
__global__ __launch_bounds__(256) void k_conv(const float* __restrict__ fe_w1,
                                              const float* __restrict__ lstm_wih,
                                              const float* __restrict__ gm_w,
                                              const float* __restrict__ fm_w,
                                              __bf16* __restrict__ Wuv, __bf16* __restrict__ Wc,
                                              __bf16* __restrict__ Wih, __bf16* __restrict__ R,
                                              int P_, int G) {
  int idx = blockIdx.x*blockDim.x + threadIdx.x;
  int nA = P_*128*64, nB = P_*64*32, nC = P_*256*64, nD = 128*64;
  if (idx < nA) {
    int k = idx & 63, j = (idx >> 6) & 127, i = idx >> 13;
    // rows 0..63: fe_w1[:, 0:64] (dst); rows 64..127: fe_w1[:, 64:128] (src)
    Wuv[idx] = (__bf16)fe_w1[(size_t)i*10240 + (j&63)*160 + (j>>6)*64 + k];
    return;
  }
  idx -= nA;
  if (idx < nB) {
    int k = idx & 31, j = (idx >> 5) & 63, i = idx >> 11;
    Wc[idx] = (__bf16)fe_w1[(size_t)i*10240 + j*160 + 128 + k];
    return;
  }
  idx -= nB;
  if (idx < nC) { Wih[idx] = (__bf16)lstm_wih[idx]; return; }
  idx -= nC;
  if (idx < nD) {
    int k = idx & 63, j = idx >> 6;
    float v = 0.f;
    if (j < G) v = gm_w[j*64 + k];
    else if (j >= 64 && j < 64 + G) v = fm_w[(j-64)*64 + k];
    R[idx] = (__bf16)v;
  }
}

// ---------------- K1: UV[n][0:64]=h@W1a^T, UV[n][64:128]=h@W1b^T ----------------
__global__ __launch_bounds__(256) void k_prep_uv(const float* __restrict__ h,
                                                 const __bf16* __restrict__ Wuv,
                                                 float* __restrict__ UV, int nGroups) {
  int wave = (blockIdx.x*blockDim.x + threadIdx.x) >> 6;
  if (wave >= nGroups) return;
  int lane = threadIdx.x & 63, row = lane & 15, quad = lane >> 4;
  int m0 = wave * 16;
  const float* arow = h + (size_t)(m0 + row)*64 + quad*8;
  bf16x8 a0 = cvt8(arow);
  bf16x8 a1 = cvt8(arow + 32);
  f32x4 z = {0.f,0.f,0.f,0.f};
  f32x4 acc[8];
  #pragma unroll
  for (int t=0;t<8;t++) acc[t] = z;
  #pragma unroll
  for (int t=0;t<8;t++) {
    const __bf16* b = Wuv + (t*16 + row)*64 + quad*8;
    bf16x8 b0 = *(const bf16x8*)b;
    bf16x8 b1 = *(const bf16x8*)(b + 32);
    acc[t] = MFMA16(a0, b0, acc[t]);
    acc[t] = MFMA16(a1, b1, acc[t]);
  }
  #pragma unroll
  for (int t=0;t<8;t++)
    #pragma unroll
    for (int r=0;r<4;r++)
      UV[(size_t)(m0 + quad*4 + r)*128 + t*16 + row] = acc[t][r];
}

// ---------------- K2: EW[e][j] = ea[e]@W1c^T + b1  (bf16) ----------------
__global__ __launch_bounds__(256) void k_ew(const float* __restrict__ ea,
                                            const __bf16* __restrict__ Wc,
                                            const float* __restrict__ b1,
                                            __bf16* __restrict__ EW, int nTiles) {
  int lane = threadIdx.x & 63, row = lane & 15, quad = lane >> 4;
  bf16x8 bfr[4];
  float bias[4];
  #pragma unroll
  for (int t=0;t<4;t++) {
    bfr[t] = *(const bf16x8*)(Wc + (t*16 + row)*32 + quad*8);
    bias[t] = b1[t*16 + row];
  }
  int nw = (gridDim.x * blockDim.x) >> 6;
  for (int tile = (blockIdx.x*blockDim.x + threadIdx.x) >> 6; tile < nTiles; tile += nw) {
    int e0 = tile * 16;
    bf16x8 a = cvt8(ea + (size_t)(e0 + row)*32 + quad*8);
    f32x4 z = {0.f,0.f,0.f,0.f};
    #pragma unroll
    for (int t=0;t<4;t++) {
      f32x4 acc = MFMA16(a, bfr[t], z);
      #pragma unroll
      for (int r=0;r<4;r++)
        EW[(size_t)(e0 + quad*4 + r)*64 + t*16 + row] = (__bf16)(acc[r] + bias[t]);
    }
  }
}

// ---------------- K3: per-edge relu(U[dst]+V[src]+EW) scatter-add ----------------
__global__ __launch_bounds__(256) void k_edge(const int* __restrict__ ei,
                                              const float* __restrict__ UV,
                                              const __bf16* __restrict__ EW,
                                              float* __restrict__ sacc,
                                              float* __restrict__ deg, int E) {
  int gw = (blockIdx.x*blockDim.x + threadIdx.x) >> 6;
  int lane = threadIdx.x & 63;
  int e0 = gw * 64;
  if (e0 >= E) return;
  int cnt = min(64, E - e0);
  int eL = e0 + min(lane, cnt - 1);
  int srcv = ei[eL];
  int dstv = ei[E + eL];
  for (int r = 0; r < cnt; r++) {
    int d = __shfl(dstv, r);
    int s = __shfl(srcv, r);
    float u  = UV[(size_t)d*128 + lane];
    float v  = UV[(size_t)s*128 + 64 + lane];
    float ew = (float)EW[(size_t)(e0 + r)*64 + lane];
    float t = u + v + ew;
    t = t > 0.f ? t : 0.f;
    unsafeAtomicAdd(&sacc[(size_t)d*64 + lane], t);
    if (lane == 0) unsafeAtomicAdd(&deg[d], 1.0f);
  }
}

// ---------------- K4: gates = h@Wih^T + s@M^T + deg*wb + b; LSTM update ----------------
__global__ __launch_bounds__(256) void k_lstm(const float* __restrict__ h_in,
                                              const float* __restrict__ sacc,
                                              const float* __restrict__ deg,
                                              const __bf16* __restrict__ Wih,
                                              const __bf16* __restrict__ Mw,
                                              const float* __restrict__ wb,
                                              const float* __restrict__ bih,
                                              const float* __restrict__ bhh,
                                              float* __restrict__ h_out,
                                              float* __restrict__ c, int nGroups) {
  int wave = (blockIdx.x*blockDim.x + threadIdx.x) >> 6;
  if (wave >= nGroups) return;
  int lane = threadIdx.x & 63, row = lane & 15, quad = lane >> 4;
  int m0 = wave * 16;
  const float* hrow = h_in + (size_t)(m0 + row)*64 + quad*8;
  const float* srow = sacc + (size_t)(m0 + row)*64 + quad*8;
  bf16x8 ah0 = cvt8(hrow), ah1 = cvt8(hrow + 32);
  bf16x8 as0 = cvt8(srow), as1 = cvt8(srow + 32);
  f32x4 z = {0.f,0.f,0.f,0.f};
  f32x4 acc[16];
  #pragma unroll
  for (int t=0;t<16;t++) acc[t] = z;
  #pragma unroll
  for (int t=0;t<16;t++) {
    const __bf16* bw = Wih + (t*16 + row)*64 + quad*8;
    const __bf16* bm = Mw  + (t*16 + row)*64 + quad*8;
    acc[t] = MFMA16(ah0, *(const bf16x8*)bw,        acc[t]);
    acc[t] = MFMA16(ah1, *(const bf16x8*)(bw + 32), acc[t]);
    acc[t] = MFMA16(as0, *(const bf16x8*)bm,        acc[t]);
    acc[t] = MFMA16(as1, *(const bf16x8*)(bm + 32), acc[t]);
  }
  #pragma unroll
  for (int r=0;r<4;r++) {
    int node = m0 + quad*4 + r;
    float dg = deg[node];
    #pragma unroll
    for (int t=0;t<4;t++) {
      int dcol = t*16 + row;
      float gi = acc[t][r]     + dg*wb[dcol]       + bih[dcol]       + bhh[dcol];
      float gf = acc[4+t][r]   + dg*wb[64+dcol]    + bih[64+dcol]    + bhh[64+dcol];
      float gg = acc[8+t][r]   + dg*wb[128+dcol]   + bih[128+dcol]   + bhh[128+dcol];
      float go = acc[12+t][r]  + dg*wb[192+dcol]   + bih[192+dcol]   + bhh[192+dcol];
      size_t ci = (size_t)node*64 + dcol;
      float cold = c[ci];
      float cn = sigf(gf)*cold + sigf(gi)*tanhf(gg);
      float hn = sigf(go)*tanhf(cn);
      c[ci] = cn;
      h_out[ci] = hn;
    }
  }
}

// ---------------- readout: out[d] = sum_n sig(h@gm^T+gb)*(h@fm^T+fb) ----------------
__global__ __launch_bounds__(256) void k_readout(const float* __restrict__ h,
                                                 const __bf16* __restrict__ R,
                                                 const float* __restrict__ gm_b,
                                                 const float* __restrict__ fm_b,
                                                 float* __restrict__ out,
                                                 int nGroups, int G) {
  int lane = threadIdx.x & 63, row = lane & 15, quad = lane >> 4;
  int wlocal = threadIdx.x >> 6;
  bf16x8 bfr0[8], bfr1[8];
  #pragma unroll
  for (int t=0;t<8;t++) {
    const __bf16* b = R + (t*16 + row)*64 + quad*8;
    bfr0[t] = *(const bf16x8*)b;
    bfr1[t] = *(const bf16x8*)(b + 32);
  }
  float local[4] = {0.f,0.f,0.f,0.f};
  int nw = (gridDim.x * blockDim.x) >> 6;
  f32x4 z = {0.f,0.f,0.f,0.f};
  for (int g = (blockIdx.x*blockDim.x + threadIdx.x) >> 6; g < nGroups; g += nw) {
    int m0 = g * 16;
    const float* hrow = h + (size_t)(m0 + row)*64 + quad*8;
    bf16x8 a0 = cvt8(hrow), a1 = cvt8(hrow + 32);
    f32x4 acc[8];
    #pragma unroll
    for (int t=0;t<8;t++) {
      acc[t] = MFMA16(a0, bfr0[t], z);
      acc[t] = MFMA16(a1, bfr1[t], acc[t]);
    }
    #pragma unroll
    for (int t=0;t<4;t++) {
      int d = t*16 + row;
      if (d < G) {
        float gb = gm_b[d], fb = fm_b[d];
        #pragma unroll
        for (int r=0;r<4;r++) {
          float gv = acc[t][r]   + gb;
          float hv = acc[4+t][r] + fb;
          local[t] += sigf(gv) * hv;
        }
      }
    }
  }
  #pragma unroll
  for (int t=0;t<4;t++) {
    float v = local[t];
    v += __shfl_xor(v, 16);
    v += __shfl_xor(v, 32);
    local[t] = v;
  }
  __shared__ float red[4][4][16];
  if (quad == 0)
    #pragma unroll
    for (int t=0;t<4;t++) red[wlocal][t][row] = local[t];
  __syncthreads();
  if (threadIdx.x < 64) {
    int d = threadIdx.x;
    if (d < G) {
      float v = red[0][d>>4][d&15] + red[1][d>>4][d&15] + red[2][d>>4][d&15] + red[3][d>>4][d&15];
      unsafeAtomicAdd(out + d, v);
    }
  }
}

extern "C" void kernel_launch(void* const* d_in, const int* in_sizes, int n_in,
                              void* d_out, int out_size, void* d_ws, size_t ws_size,
                              hipStream_t stream) {
  const float* x         = (const float*)d_in[0];
  const float* edge_attr = (const float*)d_in[1];
  const int*   edge_index= (const int*)  d_in[2];
  const float* fe_w1     = (const float*)d_in[3];
  const float* fe_b1     = (const float*)d_in[4];
  const float* fe_w2     = (const float*)d_in[5];
  const float* fe_b2     = (const float*)d_in[6];
  const float* lstm_wih  = (const float*)d_in[7];
  const float* lstm_whh  = (const float*)d_in[8];
  const float* lstm_bih  = (const float*)d_in[9];
  const float* lstm_bhh  = (const float*)d_in[10];
  const float* gm_w      = (const float*)d_in[11];
  const float* gm_b      = (const float*)d_in[12];
  const float* fm_w      = (const float*)d_in[13];
  const float* fm_b      = (const float*)d_in[14];
  float* out = (float*)d_out;

  const int N  = in_sizes[0] / 64;
  const int E  = in_sizes[1] / 32;
  const int P_ = in_sizes[3] / (64*160);
  const int G  = in_sizes[11] / 64;
  const int nGroups = N / 16;            // N=100000 -> 6250 (exact)

  // ---- workspace layout ----
  float* f = (float*)d_ws;
  float* hA  = f;                         size_t o = (size_t)N*64;
  float* hB  = f + o;                     o += (size_t)N*64;
  float* cB  = f + o;                     o += (size_t)N*64;
  float* UV  = f + o;                     o += (size_t)N*128;
  float* sB  = f + o;                     o += (size_t)N*64;
  float* deg = f + o;                     o += (size_t)N;
  float* wb  = f + o;                     o += (size_t)P_*256;
  __bf16* Wuv = (__bf16*)(f + o);
  __bf16* Wc  = Wuv + (size_t)P_*128*64;
  __bf16* Wih = Wc  + (size_t)P_*64*32;
  __bf16* Mw  = Wih + (size_t)P_*256*64;
  __bf16* Rw  = Mw  + (size_t)P_*256*64;
  __bf16* EW  = Rw  + 128*64;

  hipMemsetAsync(out, 0, (size_t)out_size*sizeof(float), stream);
  hipMemsetAsync(cB, 0, (size_t)N*64*sizeof(float), stream);

  {
    int tot = P_*256*64;
    k_prep_M<<<(tot+255)/256, 256, 0, stream>>>(lstm_whh, fe_w2, fe_b2, Mw, wb, P_);
    int tot2 = P_*128*64 + P_*64*32 + P_*256*64 + 128*64;
    k_conv<<<(tot2+255)/256, 256, 0, stream>>>(fe_w1, lstm_wih, gm_w, fm_w,
                                               Wuv, Wc, Wih, Rw, P_, G);
  }

  int nodeBlocks = (nGroups + 3) / 4;
  int edgeBlocks = (E/64 + 3) / 4;

  for (int i = 0; i < P_; i++) {
    const float* h_in = (i == 0) ? x : ((i & 1) ? hA : hB);
    float*       h_out = (i & 1) ? hB : hA;

    k_prep_uv<<<nodeBlocks, 256, 0, stream>>>(h_in, Wuv + (size_t)i*128*64, UV, nGroups);
    k_ew<<<1024, 256, 0, stream>>>(edge_attr, Wc + (size_t)i*64*32, fe_b1 + i*64, EW, E/16);
    // zero s + deg (contiguous)
    hipMemsetAsync(sB, 0, ((size_t)N*64 + N)*sizeof(float), stream);
    k_edge<<<edgeBlocks, 256, 0, stream>>>(edge_index, UV, EW, sB, deg, E);
    k_lstm<<<nodeBlocks, 256, 0, stream>>>(h_in, sB, deg,
                                           Wih + (size_t)i*256*64, Mw + (size_t)i*256*64,
                                           wb + i*256, lstm_bih + i*256, lstm_bhh + i*256,
                                           h_out, cB, nGroups);
  }

  const float* h_fin = (P_ & 1) ? hA : hB;
  k_readout<<<512, 256, 0, stream>>>(h_fin, Rw, gm_b, fm_b, out, nGroups, G);
}

// Round 2
// 1367.261 us; speedup vs baseline: 1.2065x; 1.2065x over previous
//
#include <hip/hip_runtime.h>
#include <hip/hip_bf16.h>
#include <math.h>

typedef __bf16  bf16x8 __attribute__((ext_vector_type(8)));
typedef float   f32x4  __attribute__((ext_vector_type(4)));

#define MFMA16(a,b,c) __builtin_amdgcn_mfma_f32_16x16x32_bf16((a),(b),(c),0,0,0)

__device__ __forceinline__ bf16x8 cvt8(const float* p) {
  const f32x4* q = (const f32x4*)p;
  f32x4 u = q[0], v = q[1];
  bf16x8 r;
  r[0]=(__bf16)u[0]; r[1]=(__bf16)u[1]; r[2]=(__bf16)u[2]; r[3]=(__bf16)u[3];
  r[4]=(__bf16)v[0]; r[5]=(__bf16)v[1]; r[6]=(__bf16)v[2]; r[7]=(__bf16)v[3];
  return r;
}

__device__ __forceinline__ float sigf(float x){ return 1.0f/(1.0f + __expf(-x)); }

// ---------------- weight prep ----------------
__global__ __launch_bounds__(256) void k_prep_M(const float* __restrict__ whh,
                                                const float* __restrict__ w2,
                                                const float* __restrict__ b2,
                                                __bf16* __restrict__ Mout,
                                                float* __restrict__ wb, int P_) {
  int idx = blockIdx.x*blockDim.x + threadIdx.x;
  if (idx >= P_*256*64) return;
  int c = idx & 63; int r = (idx >> 6) & 255; int i = idx >> 14;
  const float* wh  = whh + ((size_t)i*256 + r)*64;
  const float* w2i = w2  + (size_t)i*64*64;
  float acc = 0.f;
  #pragma unroll 8
  for (int j=0;j<64;j++) acc += wh[j] * w2i[j*64 + c];
  Mout[idx] = (__bf16)acc;
  if (c == 0) {
    const float* b2i = b2 + i*64;
    float a2 = 0.f;
    for (int j=0;j<64;j++) a2 += wh[j]*b2i[j];
    wb[i*256 + r] = a2;
  }
}

__global__ __launch_bounds__(256) void k_conv(const float* __restrict__ fe_w1,
                                              const float* __restrict__ lstm_wih,
                                              const float* __restrict__ gm_w,
                                              const float* __restrict__ fm_w,
                                              __bf16* __restrict__ Wuv, __bf16* __restrict__ Wc,
                                              __bf16* __restrict__ Wih, __bf16* __restrict__ R,
                                              int P_, int G) {
  int idx = blockIdx.x*blockDim.x + threadIdx.x;
  int nA = P_*128*64, nB = P_*64*32, nC = P_*256*64, nD = 128*64;
  if (idx < nA) {
    int k = idx & 63, j = (idx >> 6) & 127, i = idx >> 13;
    Wuv[idx] = (__bf16)fe_w1[(size_t)i*10240 + (j&63)*160 + (j>>6)*64 + k];
    return;
  }
  idx -= nA;
  if (idx < nB) {
    int k = idx & 31, j = (idx >> 5) & 63, i = idx >> 11;
    Wc[idx] = (__bf16)fe_w1[(size_t)i*10240 + j*160 + 128 + k];
    return;
  }
  idx -= nB;
  if (idx < nC) { Wih[idx] = (__bf16)lstm_wih[idx]; return; }
  idx -= nC;
  if (idx < nD) {
    int k = idx & 63, j = idx >> 6;
    float v = 0.f;
    if (j < G) v = gm_w[j*64 + k];
    else if (j >= 64 && j < 64 + G) v = fm_w[(j-64)*64 + k];
    R[idx] = (__bf16)v;
  }
}

// ---------------- CSR construction (once per launch) ----------------
__global__ __launch_bounds__(256) void k_hist(const int* __restrict__ ei,
                                              int* __restrict__ degi, int E) {
  int e = blockIdx.x*blockDim.x + threadIdx.x;
  if (e < E) atomicAdd(&degi[ei[E + e]], 1);
}

__global__ __launch_bounds__(256) void k_bsum(const int* __restrict__ degi,
                                              int* __restrict__ bsum, int N) {
  __shared__ int sd[256];
  int idx = blockIdx.x*256 + threadIdx.x;
  sd[threadIdx.x] = (idx < N) ? degi[idx] : 0;
  __syncthreads();
  for (int s = 128; s > 0; s >>= 1) {
    if (threadIdx.x < s) sd[threadIdx.x] += sd[threadIdx.x + s];
    __syncthreads();
  }
  if (threadIdx.x == 0) bsum[blockIdx.x] = sd[0];
}

__global__ __launch_bounds__(512) void k_bscan(int* __restrict__ bsum, int nb) {
  __shared__ int s[512];
  int t = threadIdx.x;
  s[t] = (t < nb) ? bsum[t] : 0;
  __syncthreads();
  if (t == 0) { int acc = 0; for (int i = 0; i < nb; i++) { int v = s[i]; s[i] = acc; acc += v; } }
  __syncthreads();
  if (t < nb) bsum[t] = s[t];
}

__global__ __launch_bounds__(256) void k_offs(const int* __restrict__ degi,
                                              const int* __restrict__ bsum,
                                              int* __restrict__ offs, int N) {
  __shared__ int sd[256];
  int idx = blockIdx.x*256 + threadIdx.x;
  int v = (idx < N) ? degi[idx] : 0;
  sd[threadIdx.x] = v;
  __syncthreads();
  #pragma unroll
  for (int sft = 1; sft < 256; sft <<= 1) {
    int add = (threadIdx.x >= sft) ? sd[threadIdx.x - sft] : 0;
    __syncthreads();
    sd[threadIdx.x] += add;
    __syncthreads();
  }
  if (idx <= N) offs[idx] = bsum[blockIdx.x] + sd[threadIdx.x] - v;
}

__global__ __launch_bounds__(256) void k_scatter(const int* __restrict__ ei,
                                                 const int* __restrict__ offs,
                                                 int* __restrict__ cursor,
                                                 int* __restrict__ pinv,
                                                 int* __restrict__ srcS, int E) {
  int e = blockIdx.x*blockDim.x + threadIdx.x;
  if (e >= E) return;
  int d = ei[E + e];
  int p = offs[d] + atomicAdd(&cursor[d], 1);
  pinv[e] = p;
  srcS[p] = ei[e];
}

// ---------------- K1: UV[n][0:64]=h@W1a^T, UV[n][64:128]=h@W1b^T ----------------
__global__ __launch_bounds__(256) void k_prep_uv(const float* __restrict__ h,
                                                 const __bf16* __restrict__ Wuv,
                                                 float* __restrict__ UV, int nGroups) {
  int wave = (blockIdx.x*blockDim.x + threadIdx.x) >> 6;
  if (wave >= nGroups) return;
  int lane = threadIdx.x & 63, row = lane & 15, quad = lane >> 4;
  int m0 = wave * 16;
  const float* arow = h + (size_t)(m0 + row)*64 + quad*8;
  bf16x8 a0 = cvt8(arow);
  bf16x8 a1 = cvt8(arow + 32);
  f32x4 z = {0.f,0.f,0.f,0.f};
  f32x4 acc[8];
  #pragma unroll
  for (int t=0;t<8;t++) acc[t] = z;
  #pragma unroll
  for (int t=0;t<8;t++) {
    const __bf16* b = Wuv + (t*16 + row)*64 + quad*8;
    acc[t] = MFMA16(a0, *(const bf16x8*)b,        acc[t]);
    acc[t] = MFMA16(a1, *(const bf16x8*)(b + 32), acc[t]);
  }
  #pragma unroll
  for (int t=0;t<8;t++)
    #pragma unroll
    for (int r=0;r<4;r++)
      UV[(size_t)(m0 + quad*4 + r)*128 + t*16 + row] = acc[t][r];
}

// ---------------- K2: EW[pinv[e]][j] = ea[e]@W1c^T + b1  (bf16, sorted order out) ----------------
__global__ __launch_bounds__(256) void k_ew(const float* __restrict__ ea,
                                            const __bf16* __restrict__ Wc,
                                            const float* __restrict__ b1,
                                            const int* __restrict__ pinv,
                                            __bf16* __restrict__ EW, int nTiles) {
  int lane = threadIdx.x & 63, row = lane & 15, quad = lane >> 4;
  bf16x8 bfr[4];
  float bias[4];
  #pragma unroll
  for (int t=0;t<4;t++) {
    bfr[t] = *(const bf16x8*)(Wc + (t*16 + row)*32 + quad*8);
    bias[t] = b1[t*16 + row];
  }
  int nw = (gridDim.x * blockDim.x) >> 6;
  for (int tile = (blockIdx.x*blockDim.x + threadIdx.x) >> 6; tile < nTiles; tile += nw) {
    int e0 = tile * 16;
    bf16x8 a = cvt8(ea + (size_t)(e0 + row)*32 + quad*8);
    int p[4];
    #pragma unroll
    for (int r=0;r<4;r++) p[r] = pinv[e0 + quad*4 + r];
    f32x4 z = {0.f,0.f,0.f,0.f};
    #pragma unroll
    for (int t=0;t<4;t++) {
      f32x4 acc = MFMA16(a, bfr[t], z);
      #pragma unroll
      for (int r=0;r<4;r++)
        EW[(size_t)p[r]*64 + t*16 + row] = (__bf16)(acc[r] + bias[t]);
    }
  }
}

// ---------------- K3: per-node aggregation, no atomics ----------------
__global__ __launch_bounds__(256) void k_aggr(const int* __restrict__ offs,
                                              const int* __restrict__ srcS,
                                              const float* __restrict__ UV,
                                              const __bf16* __restrict__ EW,
                                              float* __restrict__ sacc, int N) {
  int node = (blockIdx.x*blockDim.x + threadIdx.x) >> 6;
  if (node >= N) return;
  int lane = threadIdx.x & 63;
  int o0 = offs[node], o1 = offs[node+1];
  float u = UV[(size_t)node*128 + lane];
  float acc = 0.f;
  for (int base = o0; base < o1; base += 64) {
    int sv = (base + lane < o1) ? srcS[base + lane] : 0;
    int cnt = min(64, o1 - base);
    for (int r = 0; r < cnt; r++) {
      int s = __shfl(sv, r);
      float v  = UV[(size_t)s*128 + 64 + lane];
      float ew = (float)EW[(size_t)(base + r)*64 + lane];
      float t = u + v + ew;
      acc += t > 0.f ? t : 0.f;
    }
  }
  sacc[(size_t)node*64 + lane] = acc;
}

// ---------------- K4: gates + LSTM update ----------------
__global__ __launch_bounds__(256) void k_lstm(const float* __restrict__ h_in,
                                              const float* __restrict__ sacc,
                                              const int* __restrict__ offs,
                                              const __bf16* __restrict__ Wih,
                                              const __bf16* __restrict__ Mw,
                                              const float* __restrict__ wb,
                                              const float* __restrict__ bih,
                                              const float* __restrict__ bhh,
                                              float* __restrict__ h_out,
                                              float* __restrict__ c, int nGroups) {
  int wave = (blockIdx.x*blockDim.x + threadIdx.x) >> 6;
  if (wave >= nGroups) return;
  int lane = threadIdx.x & 63, row = lane & 15, quad = lane >> 4;
  int m0 = wave * 16;
  const float* hrow = h_in + (size_t)(m0 + row)*64 + quad*8;
  const float* srow = sacc + (size_t)(m0 + row)*64 + quad*8;
  bf16x8 ah0 = cvt8(hrow), ah1 = cvt8(hrow + 32);
  bf16x8 as0 = cvt8(srow), as1 = cvt8(srow + 32);
  f32x4 z = {0.f,0.f,0.f,0.f};
  f32x4 acc[16];
  #pragma unroll
  for (int t=0;t<16;t++) acc[t] = z;
  #pragma unroll
  for (int t=0;t<16;t++) {
    const __bf16* bw = Wih + (t*16 + row)*64 + quad*8;
    const __bf16* bm = Mw  + (t*16 + row)*64 + quad*8;
    acc[t] = MFMA16(ah0, *(const bf16x8*)bw,        acc[t]);
    acc[t] = MFMA16(ah1, *(const bf16x8*)(bw + 32), acc[t]);
    acc[t] = MFMA16(as0, *(const bf16x8*)bm,        acc[t]);
    acc[t] = MFMA16(as1, *(const bf16x8*)(bm + 32), acc[t]);
  }
  #pragma unroll
  for (int r=0;r<4;r++) {
    int node = m0 + quad*4 + r;
    float dg = (float)(offs[node+1] - offs[node]);
    #pragma unroll
    for (int t=0;t<4;t++) {
      int dcol = t*16 + row;
      float gi = acc[t][r]     + dg*wb[dcol]       + bih[dcol]       + bhh[dcol];
      float gf = acc[4+t][r]   + dg*wb[64+dcol]    + bih[64+dcol]    + bhh[64+dcol];
      float gg = acc[8+t][r]   + dg*wb[128+dcol]   + bih[128+dcol]   + bhh[128+dcol];
      float go = acc[12+t][r]  + dg*wb[192+dcol]   + bih[192+dcol]   + bhh[192+dcol];
      size_t ci = (size_t)node*64 + dcol;
      float cold = c[ci];
      float cn = sigf(gf)*cold + sigf(gi)*tanhf(gg);
      float hn = sigf(go)*tanhf(cn);
      c[ci] = cn;
      h_out[ci] = hn;
    }
  }
}

// ---------------- readout ----------------
__global__ __launch_bounds__(256) void k_readout(const float* __restrict__ h,
                                                 const __bf16* __restrict__ R,
                                                 const float* __restrict__ gm_b,
                                                 const float* __restrict__ fm_b,
                                                 float* __restrict__ out,
                                                 int nGroups, int G) {
  int lane = threadIdx.x & 63, row = lane & 15, quad = lane >> 4;
  int wlocal = threadIdx.x >> 6;
  bf16x8 bfr0[8], bfr1[8];
  #pragma unroll
  for (int t=0;t<8;t++) {
    const __bf16* b = R + (t*16 + row)*64 + quad*8;
    bfr0[t] = *(const bf16x8*)b;
    bfr1[t] = *(const bf16x8*)(b + 32);
  }
  float local[4] = {0.f,0.f,0.f,0.f};
  int nw = (gridDim.x * blockDim.x) >> 6;
  f32x4 z = {0.f,0.f,0.f,0.f};
  for (int g = (blockIdx.x*blockDim.x + threadIdx.x) >> 6; g < nGroups; g += nw) {
    int m0 = g * 16;
    const float* hrow = h + (size_t)(m0 + row)*64 + quad*8;
    bf16x8 a0 = cvt8(hrow), a1 = cvt8(hrow + 32);
    f32x4 acc[8];
    #pragma unroll
    for (int t=0;t<8;t++) {
      acc[t] = MFMA16(a0, bfr0[t], z);
      acc[t] = MFMA16(a1, bfr1[t], acc[t]);
    }
    #pragma unroll
    for (int t=0;t<4;t++) {
      int d = t*16 + row;
      if (d < G) {
        float gb = gm_b[d], fb = fm_b[d];
        #pragma unroll
        for (int r=0;r<4;r++) {
          float gv = acc[t][r]   + gb;
          float hv = acc[4+t][r] + fb;
          local[t] += sigf(gv) * hv;
        }
      }
    }
  }
  #pragma unroll
  for (int t=0;t<4;t++) {
    float v = local[t];
    v += __shfl_xor(v, 16);
    v += __shfl_xor(v, 32);
    local[t] = v;
  }
  __shared__ float red[4][4][16];
  if (quad == 0)
    #pragma unroll
    for (int t=0;t<4;t++) red[wlocal][t][row] = local[t];
  __syncthreads();
  if (threadIdx.x < 64) {
    int d = threadIdx.x;
    if (d < G) {
      float v = red[0][d>>4][d&15] + red[1][d>>4][d&15] + red[2][d>>4][d&15] + red[3][d>>4][d&15];
      unsafeAtomicAdd(out + d, v);
    }
  }
}

extern "C" void kernel_launch(void* const* d_in, const int* in_sizes, int n_in,
                              void* d_out, int out_size, void* d_ws, size_t ws_size,
                              hipStream_t stream) {
  const float* x         = (const float*)d_in[0];
  const float* edge_attr = (const float*)d_in[1];
  const int*   edge_index= (const int*)  d_in[2];
  const float* fe_w1     = (const float*)d_in[3];
  const float* fe_b1     = (const float*)d_in[4];
  const float* fe_w2     = (const float*)d_in[5];
  const float* fe_b2     = (const float*)d_in[6];
  const float* lstm_wih  = (const float*)d_in[7];
  const float* lstm_whh  = (const float*)d_in[8];
  const float* lstm_bih  = (const float*)d_in[9];
  const float* lstm_bhh  = (const float*)d_in[10];
  const float* gm_w      = (const float*)d_in[11];
  const float* gm_b      = (const float*)d_in[12];
  const float* fm_w      = (const float*)d_in[13];
  const float* fm_b      = (const float*)d_in[14];
  float* out = (float*)d_out;

  const int N  = in_sizes[0] / 64;
  const int E  = in_sizes[1] / 32;
  const int P_ = in_sizes[3] / (64*160);
  const int G  = in_sizes[11] / 64;
  const int nGroups = N / 16;

  // ---- workspace layout ----
  float* f = (float*)d_ws;
  float* hA  = f;                         size_t o = (size_t)N*64;
  float* hB  = f + o;                     o += (size_t)N*64;
  float* cB  = f + o;                     o += (size_t)N*64;
  float* UV  = f + o;                     o += (size_t)N*128;
  float* sB  = f + o;                     o += (size_t)N*64;
  float* wb  = f + o;                     o += (size_t)P_*256;
  int* degi   = (int*)(f + o);            o += (size_t)N;
  int* cursor = (int*)(f + o);            o += (size_t)N;
  int* offs   = (int*)(f + o);            o += (size_t)N + 1;
  int* bsum   = (int*)(f + o);            o += 512;
  int* pinv   = (int*)(f + o);            o += (size_t)E;
  int* srcS   = (int*)(f + o);            o += (size_t)E;
  __bf16* Wuv = (__bf16*)(f + o);
  __bf16* Wc  = Wuv + (size_t)P_*128*64;
  __bf16* Wih = Wc  + (size_t)P_*64*32;
  __bf16* Mw  = Wih + (size_t)P_*256*64;
  __bf16* Rw  = Mw  + (size_t)P_*256*64;
  __bf16* EW  = Rw  + 128*64;

  hipMemsetAsync(out, 0, (size_t)out_size*sizeof(float), stream);
  hipMemsetAsync(cB, 0, (size_t)N*64*sizeof(float), stream);
  hipMemsetAsync(degi, 0, (size_t)N*sizeof(int), stream);
  hipMemsetAsync(cursor, 0, (size_t)N*sizeof(int), stream);

  // weight prep
  {
    int tot = P_*256*64;
    k_prep_M<<<(tot+255)/256, 256, 0, stream>>>(lstm_whh, fe_w2, fe_b2, Mw, wb, P_);
    int tot2 = P_*128*64 + P_*64*32 + P_*256*64 + 128*64;
    k_conv<<<(tot2+255)/256, 256, 0, stream>>>(fe_w1, lstm_wih, gm_w, fm_w,
                                               Wuv, Wc, Wih, Rw, P_, G);
  }

  // CSR build (once)
  int nb = (N + 255) / 256;
  k_hist<<<(E+255)/256, 256, 0, stream>>>(edge_index, degi, E);
  k_bsum<<<nb, 256, 0, stream>>>(degi, bsum, N);
  k_bscan<<<1, 512, 0, stream>>>(bsum, nb);
  k_offs<<<nb, 256, 0, stream>>>(degi, bsum, offs, N);
  k_scatter<<<(E+255)/256, 256, 0, stream>>>(edge_index, offs, cursor, pinv, srcS, E);

  int nodeBlocks = (nGroups + 3) / 4;
  int aggrBlocks = (N + 3) / 4;

  for (int i = 0; i < P_; i++) {
    const float* h_in = (i == 0) ? x : ((i & 1) ? hA : hB);
    float*       h_out = (i & 1) ? hB : hA;

    k_prep_uv<<<nodeBlocks, 256, 0, stream>>>(h_in, Wuv + (size_t)i*128*64, UV, nGroups);
    k_ew<<<1024, 256, 0, stream>>>(edge_attr, Wc + (size_t)i*64*32, fe_b1 + i*64, pinv, EW, E/16);
    k_aggr<<<aggrBlocks, 256, 0, stream>>>(offs, srcS, UV, EW, sB, N);
    k_lstm<<<nodeBlocks, 256, 0, stream>>>(h_in, sB, offs,
                                           Wih + (size_t)i*256*64, Mw + (size_t)i*256*64,
                                           wb + i*256, lstm_bih + i*256, lstm_bhh + i*256,
                                           h_out, cB, nGroups);
  }

  const float* h_fin = (P_ & 1) ? hA : hB;
  k_readout<<<512, 256, 0, stream>>>(h_fin, Rw, gm_b, fm_b, out, nGroups, G);
}

// Round 3
// 1144.722 us; speedup vs baseline: 1.4410x; 1.1944x over previous
//
#include <hip/hip_runtime.h>
#include <hip/hip_bf16.h>
#include <math.h>

typedef __bf16  bf16x8 __attribute__((ext_vector_type(8)));
typedef float   f32x4  __attribute__((ext_vector_type(4)));

#define MFMA16(a,b,c) __builtin_amdgcn_mfma_f32_16x16x32_bf16((a),(b),(c),0,0,0)

__device__ __forceinline__ bf16x8 cvt8(const float* p) {
  const f32x4* q = (const f32x4*)p;
  f32x4 u = q[0], v = q[1];
  bf16x8 r;
  r[0]=(__bf16)u[0]; r[1]=(__bf16)u[1]; r[2]=(__bf16)u[2]; r[3]=(__bf16)u[3];
  r[4]=(__bf16)v[0]; r[5]=(__bf16)v[1]; r[6]=(__bf16)v[2]; r[7]=(__bf16)v[3];
  return r;
}

__device__ __forceinline__ float sigf(float x){ return 1.0f/(1.0f + __expf(-x)); }

// ---------------- weight prep ----------------
__global__ __launch_bounds__(256) void k_prep_M(const float* __restrict__ whh,
                                                const float* __restrict__ w2,
                                                const float* __restrict__ b2,
                                                __bf16* __restrict__ Mout,
                                                float* __restrict__ wb, int P_) {
  int idx = blockIdx.x*blockDim.x + threadIdx.x;
  if (idx >= P_*256*64) return;
  int c = idx & 63; int r = (idx >> 6) & 255; int i = idx >> 14;
  const float* wh  = whh + ((size_t)i*256 + r)*64;
  const float* w2i = w2  + (size_t)i*64*64;
  float acc = 0.f;
  #pragma unroll 8
  for (int j=0;j<64;j++) acc += wh[j] * w2i[j*64 + c];
  Mout[idx] = (__bf16)acc;
  if (c == 0) {
    const float* b2i = b2 + i*64;
    float a2 = 0.f;
    for (int j=0;j<64;j++) a2 += wh[j]*b2i[j];
    wb[i*256 + r] = a2;
  }
}

__global__ __launch_bounds__(256) void k_conv(const float* __restrict__ fe_w1,
                                              const float* __restrict__ lstm_wih,
                                              const float* __restrict__ gm_w,
                                              const float* __restrict__ fm_w,
                                              __bf16* __restrict__ Wuv, __bf16* __restrict__ Wc,
                                              __bf16* __restrict__ Wih, __bf16* __restrict__ R,
                                              int P_, int G) {
  int idx = blockIdx.x*blockDim.x + threadIdx.x;
  int nA = P_*128*64, nB = P_*64*32, nC = P_*256*64, nD = 128*64;
  if (idx < nA) {
    int k = idx & 63, j = (idx >> 6) & 127, i = idx >> 13;
    Wuv[idx] = (__bf16)fe_w1[(size_t)i*10240 + (j&63)*160 + (j>>6)*64 + k];
    return;
  }
  idx -= nA;
  if (idx < nB) {
    int k = idx & 31, j = (idx >> 5) & 63, i = idx >> 11;
    Wc[idx] = (__bf16)fe_w1[(size_t)i*10240 + j*160 + 128 + k];
    return;
  }
  idx -= nB;
  if (idx < nC) { Wih[idx] = (__bf16)lstm_wih[idx]; return; }
  idx -= nC;
  if (idx < nD) {
    int k = idx & 63, j = idx >> 6;
    float v = 0.f;
    if (j < G) v = gm_w[j*64 + k];
    else if (j >= 64 && j < 64 + G) v = fm_w[(j-64)*64 + k];
    R[idx] = (__bf16)v;
  }
}

// ---------------- CSR construction (once per launch) ----------------
__global__ __launch_bounds__(256) void k_hist(const int* __restrict__ ei,
                                              int* __restrict__ degi, int E) {
  int e = blockIdx.x*blockDim.x + threadIdx.x;
  if (e < E) atomicAdd(&degi[ei[E + e]], 1);
}

__global__ __launch_bounds__(256) void k_bsum(const int* __restrict__ degi,
                                              int* __restrict__ bsum, int N) {
  __shared__ int sd[256];
  int idx = blockIdx.x*256 + threadIdx.x;
  sd[threadIdx.x] = (idx < N) ? degi[idx] : 0;
  __syncthreads();
  for (int s = 128; s > 0; s >>= 1) {
    if (threadIdx.x < s) sd[threadIdx.x] += sd[threadIdx.x + s];
    __syncthreads();
  }
  if (threadIdx.x == 0) bsum[blockIdx.x] = sd[0];
}

// parallel exclusive scan over up to 512 block sums
__global__ __launch_bounds__(512) void k_bscan(int* __restrict__ bsum, int nb) {
  __shared__ int s[512];
  int t = threadIdx.x;
  int v = (t < nb) ? bsum[t] : 0;
  s[t] = v;
  __syncthreads();
  #pragma unroll
  for (int off = 1; off < 512; off <<= 1) {
    int a = (t >= off) ? s[t - off] : 0;
    __syncthreads();
    s[t] += a;
    __syncthreads();
  }
  if (t < nb) bsum[t] = s[t] - v;
}

__global__ __launch_bounds__(256) void k_offs(const int* __restrict__ degi,
                                              const int* __restrict__ bsum,
                                              int* __restrict__ offs, int N) {
  __shared__ int sd[256];
  int idx = blockIdx.x*256 + threadIdx.x;
  int v = (idx < N) ? degi[idx] : 0;
  sd[threadIdx.x] = v;
  __syncthreads();
  #pragma unroll
  for (int sft = 1; sft < 256; sft <<= 1) {
    int add = (threadIdx.x >= sft) ? sd[threadIdx.x - sft] : 0;
    __syncthreads();
    sd[threadIdx.x] += add;
    __syncthreads();
  }
  if (idx <= N) offs[idx] = bsum[blockIdx.x] + sd[threadIdx.x] - v;
}

__global__ __launch_bounds__(256) void k_scatter(const int* __restrict__ ei,
                                                 const int* __restrict__ offs,
                                                 int* __restrict__ cursor,
                                                 int* __restrict__ perm,
                                                 int* __restrict__ dstS,
                                                 int* __restrict__ srcS, int E) {
  int e = blockIdx.x*blockDim.x + threadIdx.x;
  if (e >= E) return;
  int d = ei[E + e];
  int p = offs[d] + atomicAdd(&cursor[d], 1);
  perm[p] = e;
  dstS[p] = d;
  srcS[p] = ei[e];
}

// permute edge_attr into sorted order, bf16 (one-time)
__global__ __launch_bounds__(256) void k_permEA(const float* __restrict__ ea,
                                                const int* __restrict__ perm,
                                                __bf16* __restrict__ EA, int E) {
  int wv = (blockIdx.x*blockDim.x + threadIdx.x) >> 6;
  int lane = threadIdx.x & 63;
  int p0 = wv * 16;
  if (p0 >= E) return;
  int r = lane >> 2, cpart = lane & 3;
  int p = p0 + r;
  if (p >= E) return;
  int e = perm[p];
  bf16x8 v = cvt8(ea + (size_t)e*32 + cpart*8);
  *(bf16x8*)(EA + (size_t)p*32 + cpart*8) = v;
}

// ---------------- K1: U=h@W1a^T, V=h@W1b^T (bf16 out) ----------------
__global__ __launch_bounds__(256) void k_prep_uv(const float* __restrict__ h,
                                                 const __bf16* __restrict__ Wuv,
                                                 __bf16* __restrict__ U,
                                                 __bf16* __restrict__ V, int nGroups) {
  int wave = (blockIdx.x*blockDim.x + threadIdx.x) >> 6;
  if (wave >= nGroups) return;
  int lane = threadIdx.x & 63, row = lane & 15, quad = lane >> 4;
  int m0 = wave * 16;
  const float* arow = h + (size_t)(m0 + row)*64 + quad*8;
  bf16x8 a0 = cvt8(arow);
  bf16x8 a1 = cvt8(arow + 32);
  f32x4 z = {0.f,0.f,0.f,0.f};
  f32x4 acc[8];
  #pragma unroll
  for (int t=0;t<8;t++) acc[t] = z;
  #pragma unroll
  for (int t=0;t<8;t++) {
    const __bf16* b = Wuv + (t*16 + row)*64 + quad*8;
    acc[t] = MFMA16(a0, *(const bf16x8*)b,        acc[t]);
    acc[t] = MFMA16(a1, *(const bf16x8*)(b + 32), acc[t]);
  }
  #pragma unroll
  for (int t=0;t<8;t++) {
    __bf16* dst = (t < 4) ? U : V;
    int f = (t & 3)*16 + row;
    #pragma unroll
    for (int r=0;r<4;r++)
      dst[(size_t)(m0 + quad*4 + r)*64 + f] = (__bf16)acc[t][r];
  }
}

// ---------------- fused edge kernel: EW on-the-fly + run-accumulate ----------------
// one wave per 64 sorted edges; EW via MFMA + LDS transpose; atomic flush per dst-run
__global__ __launch_bounds__(256) void k_edge_f(const int* __restrict__ dstS,
                                                const int* __restrict__ srcS,
                                                const __bf16* __restrict__ EA,
                                                const __bf16* __restrict__ Wc,
                                                const float* __restrict__ b1,
                                                const __bf16* __restrict__ U,
                                                const __bf16* __restrict__ V,
                                                float* __restrict__ sacc, int E) {
  __shared__ float ldsb[4][16*65];
  int wib = threadIdx.x >> 6;
  int lane = threadIdx.x & 63, row = lane & 15, quad = lane >> 4;

  bf16x8 bfr[4]; float bias[4];
  #pragma unroll
  for (int t=0;t<4;t++) {
    bfr[t] = *(const bf16x8*)(Wc + (t*16 + row)*32 + quad*8);
    bias[t] = b1[t*16 + row];
  }

  int chunk = blockIdx.x*4 + wib;
  int e0 = chunk * 64;
  if (e0 >= E) return;
  int cnt = min(64, E - e0);

  int dv = dstS[e0 + min(lane, cnt-1)];
  int sv = srcS[e0 + min(lane, cnt-1)];

  int dcur = __shfl(dv, 0);
  float u = (float)U[(size_t)dcur*64 + lane];
  float acc = 0.f;
  float* L = &ldsb[wib][0];
  f32x4 z = {0.f,0.f,0.f,0.f};

  #pragma unroll
  for (int st=0; st<4; st++) {
    if (st*16 >= cnt) break;
    // EW tile via MFMA: A = EA rows [e0+st*16 .. +16), B = Wc
    bf16x8 a = *(const bf16x8*)(EA + (size_t)(e0 + st*16 + row)*32 + quad*8);
    #pragma unroll
    for (int t=0;t<4;t++) {
      f32x4 c4 = MFMA16(a, bfr[t], z);
      #pragma unroll
      for (int r=0;r<4;r++)
        L[(quad*4 + r)*65 + t*16 + row] = c4[r] + bias[t];
    }
    // batch-prefetch V rows for this subtile
    float vv[16];
    #pragma unroll
    for (int r=0;r<16;r++) {
      int ge = st*16 + r;
      if (ge < cnt) {
        int s = __shfl(sv, ge);
        vv[r] = (float)V[(size_t)s*64 + lane];
      } else vv[r] = 0.f;
    }
    // run-length accumulate
    #pragma unroll
    for (int r=0;r<16;r++) {
      int ge = st*16 + r;
      if (ge < cnt) {
        int d = __shfl(dv, ge);
        if (d != dcur) {
          unsafeAtomicAdd(&sacc[(size_t)dcur*64 + lane], acc);
          acc = 0.f;
          dcur = d;
          u = (float)U[(size_t)dcur*64 + lane];
        }
        float ew = L[r*65 + lane];
        float t2 = u + vv[r] + ew;
        acc += t2 > 0.f ? t2 : 0.f;
      }
    }
  }
  unsafeAtomicAdd(&sacc[(size_t)dcur*64 + lane], acc);
}

// ---------------- K4: gates + LSTM update ----------------
__global__ __launch_bounds__(256) void k_lstm(const float* __restrict__ h_in,
                                              const float* __restrict__ sacc,
                                              const int* __restrict__ offs,
                                              const __bf16* __restrict__ Wih,
                                              const __bf16* __restrict__ Mw,
                                              const float* __restrict__ wb,
                                              const float* __restrict__ bih,
                                              const float* __restrict__ bhh,
                                              float* __restrict__ h_out,
                                              float* __restrict__ c, int nGroups) {
  int wave = (blockIdx.x*blockDim.x + threadIdx.x) >> 6;
  if (wave >= nGroups) return;
  int lane = threadIdx.x & 63, row = lane & 15, quad = lane >> 4;
  int m0 = wave * 16;
  const float* hrow = h_in + (size_t)(m0 + row)*64 + quad*8;
  const float* srow = sacc + (size_t)(m0 + row)*64 + quad*8;
  bf16x8 ah0 = cvt8(hrow), ah1 = cvt8(hrow + 32);
  bf16x8 as0 = cvt8(srow), as1 = cvt8(srow + 32);
  f32x4 z = {0.f,0.f,0.f,0.f};
  f32x4 acc[16];
  #pragma unroll
  for (int t=0;t<16;t++) acc[t] = z;
  #pragma unroll
  for (int t=0;t<16;t++) {
    const __bf16* bw = Wih + (t*16 + row)*64 + quad*8;
    const __bf16* bm = Mw  + (t*16 + row)*64 + quad*8;
    acc[t] = MFMA16(ah0, *(const bf16x8*)bw,        acc[t]);
    acc[t] = MFMA16(ah1, *(const bf16x8*)(bw + 32), acc[t]);
    acc[t] = MFMA16(as0, *(const bf16x8*)bm,        acc[t]);
    acc[t] = MFMA16(as1, *(const bf16x8*)(bm + 32), acc[t]);
  }
  #pragma unroll
  for (int r=0;r<4;r++) {
    int node = m0 + quad*4 + r;
    float dg = (float)(offs[node+1] - offs[node]);
    #pragma unroll
    for (int t=0;t<4;t++) {
      int dcol = t*16 + row;
      float gi = acc[t][r]     + dg*wb[dcol]       + bih[dcol]       + bhh[dcol];
      float gf = acc[4+t][r]   + dg*wb[64+dcol]    + bih[64+dcol]    + bhh[64+dcol];
      float gg = acc[8+t][r]   + dg*wb[128+dcol]   + bih[128+dcol]   + bhh[128+dcol];
      float go = acc[12+t][r]  + dg*wb[192+dcol]   + bih[192+dcol]   + bhh[192+dcol];
      size_t ci = (size_t)node*64 + dcol;
      float cold = c[ci];
      float cn = sigf(gf)*cold + sigf(gi)*tanhf(gg);
      float hn = sigf(go)*tanhf(cn);
      c[ci] = cn;
      h_out[ci] = hn;
    }
  }
}

// ---------------- readout ----------------
__global__ __launch_bounds__(256) void k_readout(const float* __restrict__ h,
                                                 const __bf16* __restrict__ R,
                                                 const float* __restrict__ gm_b,
                                                 const float* __restrict__ fm_b,
                                                 float* __restrict__ out,
                                                 int nGroups, int G) {
  int lane = threadIdx.x & 63, row = lane & 15, quad = lane >> 4;
  int wlocal = threadIdx.x >> 6;
  bf16x8 bfr0[8], bfr1[8];
  #pragma unroll
  for (int t=0;t<8;t++) {
    const __bf16* b = R + (t*16 + row)*64 + quad*8;
    bfr0[t] = *(const bf16x8*)b;
    bfr1[t] = *(const bf16x8*)(b + 32);
  }
  float local[4] = {0.f,0.f,0.f,0.f};
  int nw = (gridDim.x * blockDim.x) >> 6;
  f32x4 z = {0.f,0.f,0.f,0.f};
  for (int g = (blockIdx.x*blockDim.x + threadIdx.x) >> 6; g < nGroups; g += nw) {
    int m0 = g * 16;
    const float* hrow = h + (size_t)(m0 + row)*64 + quad*8;
    bf16x8 a0 = cvt8(hrow), a1 = cvt8(hrow + 32);
    f32x4 acc[8];
    #pragma unroll
    for (int t=0;t<8;t++) {
      acc[t] = MFMA16(a0, bfr0[t], z);
      acc[t] = MFMA16(a1, bfr1[t], acc[t]);
    }
    #pragma unroll
    for (int t=0;t<4;t++) {
      int d = t*16 + row;
      if (d < G) {
        float gb = gm_b[d], fb = fm_b[d];
        #pragma unroll
        for (int r=0;r<4;r++) {
          float gv = acc[t][r]   + gb;
          float hv = acc[4+t][r] + fb;
          local[t] += sigf(gv) * hv;
        }
      }
    }
  }
  #pragma unroll
  for (int t=0;t<4;t++) {
    float v = local[t];
    v += __shfl_xor(v, 16);
    v += __shfl_xor(v, 32);
    local[t] = v;
  }
  __shared__ float red[4][4][16];
  if (quad == 0)
    #pragma unroll
    for (int t=0;t<4;t++) red[wlocal][t][row] = local[t];
  __syncthreads();
  if (threadIdx.x < 64) {
    int d = threadIdx.x;
    if (d < G) {
      float v = red[0][d>>4][d&15] + red[1][d>>4][d&15] + red[2][d>>4][d&15] + red[3][d>>4][d&15];
      unsafeAtomicAdd(out + d, v);
    }
  }
}

extern "C" void kernel_launch(void* const* d_in, const int* in_sizes, int n_in,
                              void* d_out, int out_size, void* d_ws, size_t ws_size,
                              hipStream_t stream) {
  const float* x         = (const float*)d_in[0];
  const float* edge_attr = (const float*)d_in[1];
  const int*   edge_index= (const int*)  d_in[2];
  const float* fe_w1     = (const float*)d_in[3];
  const float* fe_b1     = (const float*)d_in[4];
  const float* fe_w2     = (const float*)d_in[5];
  const float* fe_b2     = (const float*)d_in[6];
  const float* lstm_wih  = (const float*)d_in[7];
  const float* lstm_whh  = (const float*)d_in[8];
  const float* lstm_bih  = (const float*)d_in[9];
  const float* lstm_bhh  = (const float*)d_in[10];
  const float* gm_w      = (const float*)d_in[11];
  const float* gm_b      = (const float*)d_in[12];
  const float* fm_w      = (const float*)d_in[13];
  const float* fm_b      = (const float*)d_in[14];
  float* out = (float*)d_out;

  const int N  = in_sizes[0] / 64;
  const int E  = in_sizes[1] / 32;
  const int P_ = in_sizes[3] / (64*160);
  const int G  = in_sizes[11] / 64;
  const int nGroups = N / 16;

  // ---- workspace layout (float units) ----
  float* f = (float*)d_ws;
  size_t o = 0;
  float* hA  = f + o;  o += (size_t)N*64;
  float* hB  = f + o;  o += (size_t)N*64;
  float* cB  = f + o;  o += (size_t)N*64;
  float* sB  = f + o;  o += (size_t)N*64;
  float* wb  = f + o;  o += (size_t)P_*256;
  __bf16* U  = (__bf16*)(f + o);  o += (size_t)N*32;
  __bf16* V  = (__bf16*)(f + o);  o += (size_t)N*32;
  int* degi   = (int*)(f + o);    o += (size_t)N;     // degi+cursor adjacent: one memset
  int* cursor = (int*)(f + o);    o += (size_t)N;
  int* offs   = (int*)(f + o);    o += (size_t)N + 1;
  int* bsum   = (int*)(f + o);    o += 512;
  int* perm   = (int*)(f + o);    o += (size_t)E;
  int* dstS   = (int*)(f + o);    o += (size_t)E;
  int* srcS   = (int*)(f + o);    o += (size_t)E;
  __bf16* EA  = (__bf16*)(f + o); o += ((size_t)E + 64)*16;  // sorted edge_attr, bf16, padded
  __bf16* Wuv = (__bf16*)(f + o);
  __bf16* Wc  = Wuv + (size_t)P_*128*64;
  __bf16* Wih = Wc  + (size_t)P_*64*32;
  __bf16* Mw  = Wih + (size_t)P_*256*64;
  __bf16* Rw  = Mw  + (size_t)P_*256*64;

  hipMemsetAsync(out, 0, (size_t)out_size*sizeof(float), stream);
  hipMemsetAsync(cB, 0, (size_t)N*64*sizeof(float), stream);
  hipMemsetAsync(degi, 0, (size_t)2*N*sizeof(int), stream);  // degi + cursor

  // weight prep
  {
    int tot = P_*256*64;
    k_prep_M<<<(tot+255)/256, 256, 0, stream>>>(lstm_whh, fe_w2, fe_b2, Mw, wb, P_);
    int tot2 = P_*128*64 + P_*64*32 + P_*256*64 + 128*64;
    k_conv<<<(tot2+255)/256, 256, 0, stream>>>(fe_w1, lstm_wih, gm_w, fm_w,
                                               Wuv, Wc, Wih, Rw, P_, G);
  }

  // CSR build + EA permute (once)
  int nb = (N + 255) / 256;
  k_hist<<<(E+255)/256, 256, 0, stream>>>(edge_index, degi, E);
  k_bsum<<<nb, 256, 0, stream>>>(degi, bsum, N);
  k_bscan<<<1, 512, 0, stream>>>(bsum, nb);
  k_offs<<<nb, 256, 0, stream>>>(degi, bsum, offs, N);
  k_scatter<<<(E+255)/256, 256, 0, stream>>>(edge_index, offs, cursor, perm, dstS, srcS, E);
  {
    int waves = (E + 15) / 16;
    k_permEA<<<(waves + 3) / 4, 256, 0, stream>>>(edge_attr, perm, EA, E);
  }

  int nodeBlocks = (nGroups + 3) / 4;
  int chunkBlocks = ((E + 63)/64 + 3) / 4;

  for (int i = 0; i < P_; i++) {
    const float* h_in = (i == 0) ? x : ((i & 1) ? hA : hB);
    float*       h_out = (i & 1) ? hB : hA;

    k_prep_uv<<<nodeBlocks, 256, 0, stream>>>(h_in, Wuv + (size_t)i*128*64, U, V, nGroups);
    hipMemsetAsync(sB, 0, (size_t)N*64*sizeof(float), stream);
    k_edge_f<<<chunkBlocks, 256, 0, stream>>>(dstS, srcS, EA, Wc + (size_t)i*64*32,
                                              fe_b1 + i*64, U, V, sB, E);
    k_lstm<<<nodeBlocks, 256, 0, stream>>>(h_in, sB, offs,
                                           Wih + (size_t)i*256*64, Mw + (size_t)i*256*64,
                                           wb + i*256, lstm_bih + i*256, lstm_bhh + i*256,
                                           h_out, cB, nGroups);
  }

  const float* h_fin = (P_ & 1) ? hA : hB;
  k_readout<<<512, 256, 0, stream>>>(h_fin, Rw, gm_b, fm_b, out, nGroups, G);
}

// Round 4
// 1139.577 us; speedup vs baseline: 1.4475x; 1.0045x over previous
//
#include <hip/hip_runtime.h>
#include <hip/hip_bf16.h>
#include <math.h>

typedef __bf16  bf16x8 __attribute__((ext_vector_type(8)));
typedef float   f32x4  __attribute__((ext_vector_type(4)));

#define MFMA16(a,b,c) __builtin_amdgcn_mfma_f32_16x16x32_bf16((a),(b),(c),0,0,0)

__device__ __forceinline__ bf16x8 cvt8(const float* p) {
  const f32x4* q = (const f32x4*)p;
  f32x4 u = q[0], v = q[1];
  bf16x8 r;
  r[0]=(__bf16)u[0]; r[1]=(__bf16)u[1]; r[2]=(__bf16)u[2]; r[3]=(__bf16)u[3];
  r[4]=(__bf16)v[0]; r[5]=(__bf16)v[1]; r[6]=(__bf16)v[2]; r[7]=(__bf16)v[3];
  return r;
}

__device__ __forceinline__ float sigf(float x){ return 1.0f/(1.0f + __expf(-x)); }
// saturating fast tanh: no overflow (t in (0,1])
__device__ __forceinline__ float tanhf_fast(float x){
  float ax = fabsf(x);
  float t = __expf(-2.f*ax);
  float r = (1.f - t)/(1.f + t);
  return copysignf(r, x);
}

// ---------------- fused weight prep (M=Whh@W2, wb=Whh@b2, bf16 conversions) ----------------
__global__ __launch_bounds__(256) void k_prep_all(const float* __restrict__ whh,
                                                  const float* __restrict__ w2,
                                                  const float* __restrict__ b2,
                                                  const float* __restrict__ fe_w1,
                                                  const float* __restrict__ lstm_wih,
                                                  const float* __restrict__ gm_w,
                                                  const float* __restrict__ fm_w,
                                                  __bf16* __restrict__ Mout,
                                                  float* __restrict__ wb,
                                                  __bf16* __restrict__ Wuv, __bf16* __restrict__ Wc,
                                                  __bf16* __restrict__ Wih, __bf16* __restrict__ R,
                                                  int P_, int G) {
  int idx = blockIdx.x*blockDim.x + threadIdx.x;
  int n0 = P_*256*64;
  if (idx < n0) {
    int c = idx & 63; int r = (idx >> 6) & 255; int i = idx >> 14;
    const float* wh  = whh + ((size_t)i*256 + r)*64;
    const float* w2i = w2  + (size_t)i*64*64;
    float acc = 0.f;
    #pragma unroll 8
    for (int j=0;j<64;j++) acc += wh[j] * w2i[j*64 + c];
    Mout[idx] = (__bf16)acc;
    if (c == 0) {
      const float* b2i = b2 + i*64;
      float a2 = 0.f;
      for (int j=0;j<64;j++) a2 += wh[j]*b2i[j];
      wb[i*256 + r] = a2;
    }
    return;
  }
  idx -= n0;
  int nA = P_*128*64, nB = P_*64*32, nC = P_*256*64, nD = 128*64;
  if (idx < nA) {
    int k = idx & 63, j = (idx >> 6) & 127, i = idx >> 13;
    Wuv[idx] = (__bf16)fe_w1[(size_t)i*10240 + (j&63)*160 + (j>>6)*64 + k];
    return;
  }
  idx -= nA;
  if (idx < nB) {
    int k = idx & 31, j = (idx >> 5) & 63, i = idx >> 11;
    Wc[idx] = (__bf16)fe_w1[(size_t)i*10240 + j*160 + 128 + k];
    return;
  }
  idx -= nB;
  if (idx < nC) { Wih[idx] = (__bf16)lstm_wih[idx]; return; }
  idx -= nC;
  if (idx < nD) {
    int k = idx & 63, j = idx >> 6;
    float v = 0.f;
    if (j < G) v = gm_w[j*64 + k];
    else if (j >= 64 && j < 64 + G) v = fm_w[(j-64)*64 + k];
    R[idx] = (__bf16)v;
  }
}

// ---------------- CSR construction (once per launch) ----------------
__global__ __launch_bounds__(256) void k_hist(const int* __restrict__ ei,
                                              int* __restrict__ degi, int E) {
  int e = blockIdx.x*blockDim.x + threadIdx.x;
  if (e < E) atomicAdd(&degi[ei[E + e]], 1);
}

__global__ __launch_bounds__(256) void k_bsum(const int* __restrict__ degi,
                                              int* __restrict__ bsum, int N) {
  __shared__ int sd[256];
  int idx = blockIdx.x*256 + threadIdx.x;
  sd[threadIdx.x] = (idx < N) ? degi[idx] : 0;
  __syncthreads();
  for (int s = 128; s > 0; s >>= 1) {
    if (threadIdx.x < s) sd[threadIdx.x] += sd[threadIdx.x + s];
    __syncthreads();
  }
  if (threadIdx.x == 0) bsum[blockIdx.x] = sd[0];
}

__global__ __launch_bounds__(512) void k_bscan(int* __restrict__ bsum, int nb) {
  __shared__ int s[512];
  int t = threadIdx.x;
  int v = (t < nb) ? bsum[t] : 0;
  s[t] = v;
  __syncthreads();
  #pragma unroll
  for (int off = 1; off < 512; off <<= 1) {
    int a = (t >= off) ? s[t - off] : 0;
    __syncthreads();
    s[t] += a;
    __syncthreads();
  }
  if (t < nb) bsum[t] = s[t] - v;
}

__global__ __launch_bounds__(256) void k_offs(const int* __restrict__ degi,
                                              const int* __restrict__ bsum,
                                              int* __restrict__ offs, int N) {
  __shared__ int sd[256];
  int idx = blockIdx.x*256 + threadIdx.x;
  int v = (idx < N) ? degi[idx] : 0;
  sd[threadIdx.x] = v;
  __syncthreads();
  #pragma unroll
  for (int sft = 1; sft < 256; sft <<= 1) {
    int add = (threadIdx.x >= sft) ? sd[threadIdx.x - sft] : 0;
    __syncthreads();
    sd[threadIdx.x] += add;
    __syncthreads();
  }
  if (idx <= N) offs[idx] = bsum[blockIdx.x] + sd[threadIdx.x] - v;
}

__global__ __launch_bounds__(256) void k_scatter(const int* __restrict__ ei,
                                                 const int* __restrict__ offs,
                                                 int* __restrict__ cursor,
                                                 int* __restrict__ perm,
                                                 int* __restrict__ srcS, int E) {
  int e = blockIdx.x*blockDim.x + threadIdx.x;
  if (e >= E) return;
  int d = ei[E + e];
  int p = offs[d] + atomicAdd(&cursor[d], 1);
  perm[p] = e;
  srcS[p] = ei[e];
}

// permute edge_attr into sorted order, bf16 (one-time)
__global__ __launch_bounds__(256) void k_permEA(const float* __restrict__ ea,
                                                const int* __restrict__ perm,
                                                __bf16* __restrict__ EA, int E) {
  int wv = (blockIdx.x*blockDim.x + threadIdx.x) >> 6;
  int lane = threadIdx.x & 63;
  int p0 = wv * 16;
  if (p0 >= E) return;
  int r = lane >> 2, cpart = lane & 3;
  int p = p0 + r;
  if (p >= E) return;
  int e = perm[p];
  bf16x8 v = cvt8(ea + (size_t)e*32 + cpart*8);
  *(bf16x8*)(EA + (size_t)p*32 + cpart*8) = v;
}

// ---------------- K1: U=h@W1a^T, V=h@W1b^T (bf16 out) ----------------
__global__ __launch_bounds__(256) void k_prep_uv(const float* __restrict__ h,
                                                 const __bf16* __restrict__ Wuv,
                                                 __bf16* __restrict__ U,
                                                 __bf16* __restrict__ V, int nGroups) {
  int wave = (blockIdx.x*blockDim.x + threadIdx.x) >> 6;
  if (wave >= nGroups) return;
  int lane = threadIdx.x & 63, row = lane & 15, quad = lane >> 4;
  int m0 = wave * 16;
  const float* arow = h + (size_t)(m0 + row)*64 + quad*8;
  bf16x8 a0 = cvt8(arow);
  bf16x8 a1 = cvt8(arow + 32);
  f32x4 z = {0.f,0.f,0.f,0.f};
  f32x4 acc[8];
  #pragma unroll
  for (int t=0;t<8;t++) acc[t] = z;
  #pragma unroll
  for (int t=0;t<8;t++) {
    const __bf16* b = Wuv + (t*16 + row)*64 + quad*8;
    acc[t] = MFMA16(a0, *(const bf16x8*)b,        acc[t]);
    acc[t] = MFMA16(a1, *(const bf16x8*)(b + 32), acc[t]);
  }
  #pragma unroll
  for (int t=0;t<8;t++) {
    __bf16* dst = (t < 4) ? U : V;
    int f = (t & 3)*16 + row;
    #pragma unroll
    for (int r=0;r<4;r++)
      dst[(size_t)(m0 + quad*4 + r)*64 + f] = (__bf16)acc[t][r];
  }
}

// ---------------- fused per-node aggregation: one wave per node, CSR, no atomics ----------------
__global__ __launch_bounds__(256) void k_aggr_f(const int* __restrict__ offs,
                                                const int* __restrict__ srcS,
                                                const __bf16* __restrict__ EA,
                                                const __bf16* __restrict__ Wc,
                                                const float* __restrict__ b1,
                                                const __bf16* __restrict__ U,
                                                const __bf16* __restrict__ V,
                                                float* __restrict__ sacc, int N) {
  __shared__ float ldsb[4][16*68];   // stride 68: 4*68 % 32 == 16 -> 2 lanes/bank (free)
  int wib = threadIdx.x >> 6;
  int lane = threadIdx.x & 63, row = lane & 15, quad = lane >> 4;

  bf16x8 bfr[4]; float bias[4];
  #pragma unroll
  for (int t=0;t<4;t++) {
    bfr[t] = *(const bf16x8*)(Wc + (t*16 + row)*32 + quad*8);
    bias[t] = b1[t*16 + row];
  }

  int node = blockIdx.x*4 + wib;
  if (node >= N) return;
  int o0 = offs[node], o1 = offs[node+1];

  float u = (float)U[(size_t)node*64 + lane];
  float acc = 0.f;
  float* L = &ldsb[wib][0];
  f32x4 z = {0.f,0.f,0.f,0.f};

  for (int base = o0; base < o1; base += 16) {
    // EW tile via MFMA (rows may overrun into next node's edges; EA padded past E)
    bf16x8 a = *(const bf16x8*)(EA + (size_t)(base + row)*32 + quad*8);
    #pragma unroll
    for (int t=0;t<4;t++) {
      f32x4 c4 = MFMA16(a, bfr[t], z);
      #pragma unroll
      for (int r=0;r<4;r++)
        L[(quad*4 + r)*68 + t*16 + row] = c4[r] + bias[t];
    }
    // batch V gathers for this tile
    int sv = srcS[min(base + (lane & 15), o1 - 1)];
    float vv[16];
    #pragma unroll
    for (int r=0;r<16;r++) {
      int s = __shfl(sv, r);
      vv[r] = (base + r < o1) ? (float)V[(size_t)s*64 + lane] : 0.f;
    }
    // accumulate relu(u + v + ew)
    #pragma unroll
    for (int r=0;r<16;r++) {
      if (base + r < o1) {
        float t2 = u + vv[r] + L[r*68 + lane];
        acc += t2 > 0.f ? t2 : 0.f;
      }
    }
  }
  sacc[(size_t)node*64 + lane] = acc;
}

// ---------------- K4: gates + LSTM update ----------------
__global__ __launch_bounds__(256) void k_lstm(const float* __restrict__ h_in,
                                              const float* __restrict__ sacc,
                                              const int* __restrict__ offs,
                                              const __bf16* __restrict__ Wih,
                                              const __bf16* __restrict__ Mw,
                                              const float* __restrict__ wb,
                                              const float* __restrict__ bih,
                                              const float* __restrict__ bhh,
                                              float* __restrict__ h_out,
                                              float* __restrict__ c, int nGroups) {
  int wave = (blockIdx.x*blockDim.x + threadIdx.x) >> 6;
  if (wave >= nGroups) return;
  int lane = threadIdx.x & 63, row = lane & 15, quad = lane >> 4;
  int m0 = wave * 16;
  const float* hrow = h_in + (size_t)(m0 + row)*64 + quad*8;
  const float* srow = sacc + (size_t)(m0 + row)*64 + quad*8;
  bf16x8 ah0 = cvt8(hrow), ah1 = cvt8(hrow + 32);
  bf16x8 as0 = cvt8(srow), as1 = cvt8(srow + 32);
  f32x4 z = {0.f,0.f,0.f,0.f};
  f32x4 acc[16];
  #pragma unroll
  for (int t=0;t<16;t++) acc[t] = z;
  #pragma unroll
  for (int t=0;t<16;t++) {
    const __bf16* bw = Wih + (t*16 + row)*64 + quad*8;
    const __bf16* bm = Mw  + (t*16 + row)*64 + quad*8;
    acc[t] = MFMA16(ah0, *(const bf16x8*)bw,        acc[t]);
    acc[t] = MFMA16(ah1, *(const bf16x8*)(bw + 32), acc[t]);
    acc[t] = MFMA16(as0, *(const bf16x8*)bm,        acc[t]);
    acc[t] = MFMA16(as1, *(const bf16x8*)(bm + 32), acc[t]);
  }
  #pragma unroll
  for (int r=0;r<4;r++) {
    int node = m0 + quad*4 + r;
    float dg = (float)(offs[node+1] - offs[node]);
    #pragma unroll
    for (int t=0;t<4;t++) {
      int dcol = t*16 + row;
      float gi = acc[t][r]     + dg*wb[dcol]       + bih[dcol]       + bhh[dcol];
      float gf = acc[4+t][r]   + dg*wb[64+dcol]    + bih[64+dcol]    + bhh[64+dcol];
      float gg = acc[8+t][r]   + dg*wb[128+dcol]   + bih[128+dcol]   + bhh[128+dcol];
      float go = acc[12+t][r]  + dg*wb[192+dcol]   + bih[192+dcol]   + bhh[192+dcol];
      size_t ci = (size_t)node*64 + dcol;
      float cold = c[ci];
      float cn = sigf(gf)*cold + sigf(gi)*tanhf_fast(gg);
      float hn = sigf(go)*tanhf_fast(cn);
      c[ci] = cn;
      h_out[ci] = hn;
    }
  }
}

// ---------------- readout ----------------
__global__ __launch_bounds__(256) void k_readout(const float* __restrict__ h,
                                                 const __bf16* __restrict__ R,
                                                 const float* __restrict__ gm_b,
                                                 const float* __restrict__ fm_b,
                                                 float* __restrict__ out,
                                                 int nGroups, int G) {
  int lane = threadIdx.x & 63, row = lane & 15, quad = lane >> 4;
  int wlocal = threadIdx.x >> 6;
  bf16x8 bfr0[8], bfr1[8];
  #pragma unroll
  for (int t=0;t<8;t++) {
    const __bf16* b = R + (t*16 + row)*64 + quad*8;
    bfr0[t] = *(const bf16x8*)b;
    bfr1[t] = *(const bf16x8*)(b + 32);
  }
  float local[4] = {0.f,0.f,0.f,0.f};
  int nw = (gridDim.x * blockDim.x) >> 6;
  f32x4 z = {0.f,0.f,0.f,0.f};
  for (int g = (blockIdx.x*blockDim.x + threadIdx.x) >> 6; g < nGroups; g += nw) {
    int m0 = g * 16;
    const float* hrow = h + (size_t)(m0 + row)*64 + quad*8;
    bf16x8 a0 = cvt8(hrow), a1 = cvt8(hrow + 32);
    f32x4 acc[8];
    #pragma unroll
    for (int t=0;t<8;t++) {
      acc[t] = MFMA16(a0, bfr0[t], z);
      acc[t] = MFMA16(a1, bfr1[t], acc[t]);
    }
    #pragma unroll
    for (int t=0;t<4;t++) {
      int d = t*16 + row;
      if (d < G) {
        float gb = gm_b[d], fb = fm_b[d];
        #pragma unroll
        for (int r=0;r<4;r++) {
          float gv = acc[t][r]   + gb;
          float hv = acc[4+t][r] + fb;
          local[t] += sigf(gv) * hv;
        }
      }
    }
  }
  #pragma unroll
  for (int t=0;t<4;t++) {
    float v = local[t];
    v += __shfl_xor(v, 16);
    v += __shfl_xor(v, 32);
    local[t] = v;
  }
  __shared__ float red[4][4][16];
  if (quad == 0)
    #pragma unroll
    for (int t=0;t<4;t++) red[wlocal][t][row] = local[t];
  __syncthreads();
  if (threadIdx.x < 64) {
    int d = threadIdx.x;
    if (d < G) {
      float v = red[0][d>>4][d&15] + red[1][d>>4][d&15] + red[2][d>>4][d&15] + red[3][d>>4][d&15];
      unsafeAtomicAdd(out + d, v);
    }
  }
}

extern "C" void kernel_launch(void* const* d_in, const int* in_sizes, int n_in,
                              void* d_out, int out_size, void* d_ws, size_t ws_size,
                              hipStream_t stream) {
  const float* x         = (const float*)d_in[0];
  const float* edge_attr = (const float*)d_in[1];
  const int*   edge_index= (const int*)  d_in[2];
  const float* fe_w1     = (const float*)d_in[3];
  const float* fe_b1     = (const float*)d_in[4];
  const float* fe_w2     = (const float*)d_in[5];
  const float* fe_b2     = (const float*)d_in[6];
  const float* lstm_wih  = (const float*)d_in[7];
  const float* lstm_whh  = (const float*)d_in[8];
  const float* lstm_bih  = (const float*)d_in[9];
  const float* lstm_bhh  = (const float*)d_in[10];
  const float* gm_w      = (const float*)d_in[11];
  const float* gm_b      = (const float*)d_in[12];
  const float* fm_w      = (const float*)d_in[13];
  const float* fm_b      = (const float*)d_in[14];
  float* out = (float*)d_out;

  const int N  = in_sizes[0] / 64;
  const int E  = in_sizes[1] / 32;
  const int P_ = in_sizes[3] / (64*160);
  const int G  = in_sizes[11] / 64;
  const int nGroups = N / 16;

  // ---- workspace layout (float units) ----
  float* f = (float*)d_ws;
  size_t o = 0;
  float* hA  = f + o;  o += (size_t)N*64;
  float* hB  = f + o;  o += (size_t)N*64;
  float* cB  = f + o;  o += (size_t)N*64;
  float* sB  = f + o;  o += (size_t)N*64;
  float* wb  = f + o;  o += (size_t)P_*256;
  __bf16* U  = (__bf16*)(f + o);  o += (size_t)N*32;
  __bf16* V  = (__bf16*)(f + o);  o += (size_t)N*32;
  int* degi   = (int*)(f + o);    o += (size_t)N;     // degi+cursor adjacent: one memset
  int* cursor = (int*)(f + o);    o += (size_t)N;
  int* offs   = (int*)(f + o);    o += (size_t)N + 1;
  int* bsum   = (int*)(f + o);    o += 512;
  int* perm   = (int*)(f + o);    o += (size_t)E;
  int* srcS   = (int*)(f + o);    o += (size_t)E;
  __bf16* EA  = (__bf16*)(f + o); o += ((size_t)E + 64)*16;  // sorted edge_attr, bf16, padded
  __bf16* Wuv = (__bf16*)(f + o);
  __bf16* Wc  = Wuv + (size_t)P_*128*64;
  __bf16* Wih = Wc  + (size_t)P_*64*32;
  __bf16* Mw  = Wih + (size_t)P_*256*64;
  __bf16* Rw  = Mw  + (size_t)P_*256*64;

  hipMemsetAsync(out, 0, (size_t)out_size*sizeof(float), stream);
  hipMemsetAsync(cB, 0, (size_t)N*64*sizeof(float), stream);
  hipMemsetAsync(degi, 0, (size_t)2*N*sizeof(int), stream);  // degi + cursor

  // fused weight prep
  {
    int tot = P_*256*64 + P_*128*64 + P_*64*32 + P_*256*64 + 128*64;
    k_prep_all<<<(tot+255)/256, 256, 0, stream>>>(lstm_whh, fe_w2, fe_b2, fe_w1, lstm_wih,
                                                  gm_w, fm_w, Mw, wb, Wuv, Wc, Wih, Rw, P_, G);
  }

  // CSR build + EA permute (once)
  int nb = (N + 255) / 256;
  k_hist<<<(E+255)/256, 256, 0, stream>>>(edge_index, degi, E);
  k_bsum<<<nb, 256, 0, stream>>>(degi, bsum, N);
  k_bscan<<<1, 512, 0, stream>>>(bsum, nb);
  k_offs<<<nb, 256, 0, stream>>>(degi, bsum, offs, N);
  k_scatter<<<(E+255)/256, 256, 0, stream>>>(edge_index, offs, cursor, perm, srcS, E);
  {
    int waves = (E + 15) / 16;
    k_permEA<<<(waves + 3) / 4, 256, 0, stream>>>(edge_attr, perm, EA, E);
  }

  int nodeBlocks = (nGroups + 3) / 4;
  int aggrBlocks = (N + 3) / 4;

  for (int i = 0; i < P_; i++) {
    const float* h_in = (i == 0) ? x : ((i & 1) ? hA : hB);
    float*       h_out = (i & 1) ? hB : hA;

    k_prep_uv<<<nodeBlocks, 256, 0, stream>>>(h_in, Wuv + (size_t)i*128*64, U, V, nGroups);
    k_aggr_f<<<aggrBlocks, 256, 0, stream>>>(offs, srcS, EA, Wc + (size_t)i*64*32,
                                             fe_b1 + i*64, U, V, sB, N);
    k_lstm<<<nodeBlocks, 256, 0, stream>>>(h_in, sB, offs,
                                           Wih + (size_t)i*256*64, Mw + (size_t)i*256*64,
                                           wb + i*256, lstm_bih + i*256, lstm_bhh + i*256,
                                           h_out, cB, nGroups);
  }

  const float* h_fin = (P_ & 1) ? hA : hB;
  k_readout<<<512, 256, 0, stream>>>(h_fin, Rw, gm_b, fm_b, out, nGroups, G);
}

// Round 5
// 1047.192 us; speedup vs baseline: 1.5752x; 1.0882x over previous
//
#include <hip/hip_runtime.h>
#include <hip/hip_bf16.h>
#include <math.h>

typedef __bf16  bf16x8 __attribute__((ext_vector_type(8)));
typedef float   f32x4  __attribute__((ext_vector_type(4)));

#define MFMA16(a,b,c) __builtin_amdgcn_mfma_f32_16x16x32_bf16((a),(b),(c),0,0,0)

__device__ __forceinline__ bf16x8 cvt8(const float* p) {
  const f32x4* q = (const f32x4*)p;
  f32x4 u = q[0], v = q[1];
  bf16x8 r;
  r[0]=(__bf16)u[0]; r[1]=(__bf16)u[1]; r[2]=(__bf16)u[2]; r[3]=(__bf16)u[3];
  r[4]=(__bf16)v[0]; r[5]=(__bf16)v[1]; r[6]=(__bf16)v[2]; r[7]=(__bf16)v[3];
  return r;
}

__device__ __forceinline__ float sigf(float x){ return 1.0f/(1.0f + __expf(-x)); }
// saturating fast tanh: no overflow (t in (0,1])
__device__ __forceinline__ float tanhf_fast(float x){
  float ax = fabsf(x);
  float t = __expf(-2.f*ax);
  float r = (1.f - t)/(1.f + t);
  return copysignf(r, x);
}

// ---------------- fused weight prep (M=Whh@W2, wb=Whh@b2, bf16 conversions) ----------------
__global__ __launch_bounds__(256) void k_prep_all(const float* __restrict__ whh,
                                                  const float* __restrict__ w2,
                                                  const float* __restrict__ b2,
                                                  const float* __restrict__ fe_w1,
                                                  const float* __restrict__ lstm_wih,
                                                  const float* __restrict__ gm_w,
                                                  const float* __restrict__ fm_w,
                                                  __bf16* __restrict__ Mout,
                                                  float* __restrict__ wb,
                                                  __bf16* __restrict__ Wuv, __bf16* __restrict__ Wc,
                                                  __bf16* __restrict__ Wih, __bf16* __restrict__ R,
                                                  int P_, int G) {
  int idx = blockIdx.x*blockDim.x + threadIdx.x;
  int n0 = P_*256*64;
  if (idx < n0) {
    int c = idx & 63; int r = (idx >> 6) & 255; int i = idx >> 14;
    const float* wh  = whh + ((size_t)i*256 + r)*64;
    const float* w2i = w2  + (size_t)i*64*64;
    float acc = 0.f;
    #pragma unroll 8
    for (int j=0;j<64;j++) acc += wh[j] * w2i[j*64 + c];
    Mout[idx] = (__bf16)acc;
    if (c == 0) {
      const float* b2i = b2 + i*64;
      float a2 = 0.f;
      for (int j=0;j<64;j++) a2 += wh[j]*b2i[j];
      wb[i*256 + r] = a2;
    }
    return;
  }
  idx -= n0;
  int nA = P_*128*64, nB = P_*64*32, nC = P_*256*64, nD = 128*64;
  if (idx < nA) {
    int k = idx & 63, j = (idx >> 6) & 127, i = idx >> 13;
    Wuv[idx] = (__bf16)fe_w1[(size_t)i*10240 + (j&63)*160 + (j>>6)*64 + k];
    return;
  }
  idx -= nA;
  if (idx < nB) {
    int k = idx & 31, j = (idx >> 5) & 63, i = idx >> 11;
    Wc[idx] = (__bf16)fe_w1[(size_t)i*10240 + j*160 + 128 + k];
    return;
  }
  idx -= nB;
  if (idx < nC) { Wih[idx] = (__bf16)lstm_wih[idx]; return; }
  idx -= nC;
  if (idx < nD) {
    int k = idx & 63, j = idx >> 6;
    float v = 0.f;
    if (j < G) v = gm_w[j*64 + k];
    else if (j >= 64 && j < 64 + G) v = fm_w[(j-64)*64 + k];
    R[idx] = (__bf16)v;
  }
}

// ---------------- CSR construction (once per launch) ----------------
__global__ __launch_bounds__(256) void k_hist(const int* __restrict__ ei,
                                              int* __restrict__ degi, int E) {
  int e = blockIdx.x*blockDim.x + threadIdx.x;
  if (e < E) atomicAdd(&degi[ei[E + e]], 1);
}

__global__ __launch_bounds__(256) void k_bsum(const int* __restrict__ degi,
                                              int* __restrict__ bsum, int N) {
  __shared__ int sd[256];
  int idx = blockIdx.x*256 + threadIdx.x;
  sd[threadIdx.x] = (idx < N) ? degi[idx] : 0;
  __syncthreads();
  for (int s = 128; s > 0; s >>= 1) {
    if (threadIdx.x < s) sd[threadIdx.x] += sd[threadIdx.x + s];
    __syncthreads();
  }
  if (threadIdx.x == 0) bsum[blockIdx.x] = sd[0];
}

__global__ __launch_bounds__(512) void k_bscan(int* __restrict__ bsum, int nb) {
  __shared__ int s[512];
  int t = threadIdx.x;
  int v = (t < nb) ? bsum[t] : 0;
  s[t] = v;
  __syncthreads();
  #pragma unroll
  for (int off = 1; off < 512; off <<= 1) {
    int a = (t >= off) ? s[t - off] : 0;
    __syncthreads();
    s[t] += a;
    __syncthreads();
  }
  if (t < nb) bsum[t] = s[t] - v;
}

__global__ __launch_bounds__(256) void k_offs(const int* __restrict__ degi,
                                              const int* __restrict__ bsum,
                                              int* __restrict__ offs, int N) {
  __shared__ int sd[256];
  int idx = blockIdx.x*256 + threadIdx.x;
  int v = (idx < N) ? degi[idx] : 0;
  sd[threadIdx.x] = v;
  __syncthreads();
  #pragma unroll
  for (int sft = 1; sft < 256; sft <<= 1) {
    int add = (threadIdx.x >= sft) ? sd[threadIdx.x - sft] : 0;
    __syncthreads();
    sd[threadIdx.x] += add;
    __syncthreads();
  }
  if (idx <= N) offs[idx] = bsum[blockIdx.x] + sd[threadIdx.x] - v;
}

__global__ __launch_bounds__(256) void k_scatter(const int* __restrict__ ei,
                                                 const int* __restrict__ offs,
                                                 int* __restrict__ cursor,
                                                 int* __restrict__ perm,
                                                 int* __restrict__ srcS, int E) {
  int e = blockIdx.x*blockDim.x + threadIdx.x;
  if (e >= E) return;
  int d = ei[E + e];
  int p = offs[d] + atomicAdd(&cursor[d], 1);
  perm[p] = e;
  srcS[p] = ei[e];
}

// permute edge_attr into sorted order, bf16 (one-time)
__global__ __launch_bounds__(256) void k_permEA(const float* __restrict__ ea,
                                                const int* __restrict__ perm,
                                                __bf16* __restrict__ EA, int E) {
  int wv = (blockIdx.x*blockDim.x + threadIdx.x) >> 6;
  int lane = threadIdx.x & 63;
  int p0 = wv * 16;
  if (p0 >= E) return;
  int r = lane >> 2, cpart = lane & 3;
  int p = p0 + r;
  if (p >= E) return;
  int e = perm[p];
  bf16x8 v = cvt8(ea + (size_t)e*32 + cpart*8);
  *(bf16x8*)(EA + (size_t)p*32 + cpart*8) = v;
}

// ---------------- K1: U=h@W1a^T, V=h@W1b^T (bf16 out) ----------------
__global__ __launch_bounds__(256) void k_prep_uv(const float* __restrict__ h,
                                                 const __bf16* __restrict__ Wuv,
                                                 __bf16* __restrict__ U,
                                                 __bf16* __restrict__ V, int nGroups) {
  int wave = (blockIdx.x*blockDim.x + threadIdx.x) >> 6;
  if (wave >= nGroups) return;
  int lane = threadIdx.x & 63, row = lane & 15, quad = lane >> 4;
  int m0 = wave * 16;
  const float* arow = h + (size_t)(m0 + row)*64 + quad*8;
  bf16x8 a0 = cvt8(arow);
  bf16x8 a1 = cvt8(arow + 32);
  f32x4 z = {0.f,0.f,0.f,0.f};
  f32x4 acc[8];
  #pragma unroll
  for (int t=0;t<8;t++) acc[t] = z;
  #pragma unroll
  for (int t=0;t<8;t++) {
    const __bf16* b = Wuv + (t*16 + row)*64 + quad*8;
    acc[t] = MFMA16(a0, *(const bf16x8*)b,        acc[t]);
    acc[t] = MFMA16(a1, *(const bf16x8*)(b + 32), acc[t]);
  }
  #pragma unroll
  for (int t=0;t<8;t++) {
    __bf16* dst = (t < 4) ? U : V;
    int f = (t & 3)*16 + row;
    #pragma unroll
    for (int r=0;r<4;r++)
      dst[(size_t)(m0 + quad*4 + r)*64 + f] = (__bf16)acc[t][r];
  }
}

// ---------------- fused per-node aggregation: one wave per node, CSR, pipelined ----------------
__global__ __launch_bounds__(256) void k_aggr_f(const int* __restrict__ offs,
                                                const int* __restrict__ srcS,
                                                const __bf16* __restrict__ EA,
                                                const __bf16* __restrict__ Wc,
                                                const float* __restrict__ b1,
                                                const __bf16* __restrict__ U,
                                                const __bf16* __restrict__ V,
                                                float* __restrict__ sacc, int N) {
  __shared__ float ldsb[4][16*68];   // stride 68: conflict-free for this pattern
  int wib = threadIdx.x >> 6;
  int lane = threadIdx.x & 63, row = lane & 15, quad = lane >> 4;

  int node = blockIdx.x*4 + wib;
  if (node >= N) return;
  int o0 = offs[node], o1 = offs[node+1];

  // tile-0 loads ASAP (longest dependency chain: offs -> srcS -> V gather)
  int sv = 0; bf16x8 a;
  if (o0 < o1) {
    sv = srcS[min(o0 + (lane & 15), o1 - 1)];
    a  = *(const bf16x8*)(EA + (size_t)(o0 + row)*32 + quad*8);
  }

  bf16x8 bfr[4]; float bias[4];
  #pragma unroll
  for (int t=0;t<4;t++) {
    bfr[t] = *(const bf16x8*)(Wc + (t*16 + row)*32 + quad*8);
    bias[t] = b1[t*16 + row];
  }
  float u = (float)U[(size_t)node*64 + lane];

  float acc = 0.f;
  float* L = &ldsb[wib][0];
  f32x4 z = {0.f,0.f,0.f,0.f};

  for (int base = o0; base < o1; base += 16) {
    // V gathers first — longest latency, overlap with MFMA + LDS below
    float vv[16];
    #pragma unroll
    for (int r=0;r<16;r++) {
      int s = __shfl(sv, r);
      vv[r] = (base + r < o1) ? (float)V[(size_t)s*64 + lane] : 0.f;
    }
    // prefetch next tile's srcS + EA
    int svN = 0; bf16x8 aN;
    bool more = (base + 16) < o1;
    if (more) {
      svN = srcS[min(base + 16 + (lane & 15), o1 - 1)];
      aN  = *(const bf16x8*)(EA + (size_t)(base + 16 + row)*32 + quad*8);
    }
    // EW tile via MFMA + LDS transpose
    #pragma unroll
    for (int t=0;t<4;t++) {
      f32x4 c4 = MFMA16(a, bfr[t], z);
      #pragma unroll
      for (int r=0;r<4;r++)
        L[(quad*4 + r)*68 + t*16 + row] = c4[r] + bias[t];
    }
    // accumulate relu(u + v + ew)
    #pragma unroll
    for (int r=0;r<16;r++) {
      if (base + r < o1) {
        float t2 = u + vv[r] + L[r*68 + lane];
        acc += t2 > 0.f ? t2 : 0.f;
      }
    }
    sv = svN; a = aN;
  }
  sacc[(size_t)node*64 + lane] = acc;
}

// ---------------- K4: gates + LSTM update (all loads hoisted) ----------------
__global__ __launch_bounds__(256) void k_lstm(const float* __restrict__ h_in,
                                              const float* __restrict__ sacc,
                                              const int* __restrict__ offs,
                                              const __bf16* __restrict__ Wih,
                                              const __bf16* __restrict__ Mw,
                                              const float* __restrict__ wb,
                                              const float* __restrict__ bih,
                                              const float* __restrict__ bhh,
                                              float* __restrict__ h_out,
                                              float* __restrict__ c, int nGroups,
                                              int has_c, int write_c) {
  int wave = (blockIdx.x*blockDim.x + threadIdx.x) >> 6;
  if (wave >= nGroups) return;
  int lane = threadIdx.x & 63, row = lane & 15, quad = lane >> 4;
  int m0 = wave * 16;

  // ---- prefetch everything the epilogue needs (independent loads, issued early) ----
  float wbv[4][4], bsv[4][4];
  #pragma unroll
  for (int g=0; g<4; g++)
    #pragma unroll
    for (int t=0; t<4; t++) {
      int dcol = g*64 + t*16 + row;
      wbv[g][t] = wb[dcol];
      bsv[g][t] = bih[dcol] + bhh[dcol];
    }
  float dgv[4];
  #pragma unroll
  for (int r=0;r<4;r++) {
    int node = m0 + quad*4 + r;
    dgv[r] = (float)(offs[node+1] - offs[node]);
  }
  float cold[4][4];   // [t][r]
  if (has_c) {
    #pragma unroll
    for (int t=0;t<4;t++)
      #pragma unroll
      for (int r=0;r<4;r++)
        cold[t][r] = c[(size_t)(m0 + quad*4 + r)*64 + t*16 + row];
  } else {
    #pragma unroll
    for (int t=0;t<4;t++)
      #pragma unroll
      for (int r=0;r<4;r++) cold[t][r] = 0.f;
  }

  const float* hrow = h_in + (size_t)(m0 + row)*64 + quad*8;
  const float* srow = sacc + (size_t)(m0 + row)*64 + quad*8;
  bf16x8 ah0 = cvt8(hrow), ah1 = cvt8(hrow + 32);
  bf16x8 as0 = cvt8(srow), as1 = cvt8(srow + 32);
  f32x4 z = {0.f,0.f,0.f,0.f};
  f32x4 acc[16];
  #pragma unroll
  for (int t=0;t<16;t++) acc[t] = z;
  #pragma unroll
  for (int t=0;t<16;t++) {
    const __bf16* bw = Wih + (t*16 + row)*64 + quad*8;
    const __bf16* bm = Mw  + (t*16 + row)*64 + quad*8;
    acc[t] = MFMA16(ah0, *(const bf16x8*)bw,        acc[t]);
    acc[t] = MFMA16(ah1, *(const bf16x8*)(bw + 32), acc[t]);
    acc[t] = MFMA16(as0, *(const bf16x8*)bm,        acc[t]);
    acc[t] = MFMA16(as1, *(const bf16x8*)(bm + 32), acc[t]);
  }
  // ---- pure-compute epilogue, fire-and-forget stores ----
  #pragma unroll
  for (int r=0;r<4;r++) {
    int node = m0 + quad*4 + r;
    float dg = dgv[r];
    #pragma unroll
    for (int t=0;t<4;t++) {
      float gi = acc[t][r]     + dg*wbv[0][t] + bsv[0][t];
      float gf = acc[4+t][r]   + dg*wbv[1][t] + bsv[1][t];
      float gg = acc[8+t][r]   + dg*wbv[2][t] + bsv[2][t];
      float go = acc[12+t][r]  + dg*wbv[3][t] + bsv[3][t];
      size_t ci = (size_t)node*64 + t*16 + row;
      float cn = sigf(gf)*cold[t][r] + sigf(gi)*tanhf_fast(gg);
      float hn = sigf(go)*tanhf_fast(cn);
      if (write_c) c[ci] = cn;
      h_out[ci] = hn;
    }
  }
}

// ---------------- readout ----------------
__global__ __launch_bounds__(256) void k_readout(const float* __restrict__ h,
                                                 const __bf16* __restrict__ R,
                                                 const float* __restrict__ gm_b,
                                                 const float* __restrict__ fm_b,
                                                 float* __restrict__ out,
                                                 int nGroups, int G) {
  int lane = threadIdx.x & 63, row = lane & 15, quad = lane >> 4;
  int wlocal = threadIdx.x >> 6;
  bf16x8 bfr0[8], bfr1[8];
  #pragma unroll
  for (int t=0;t<8;t++) {
    const __bf16* b = R + (t*16 + row)*64 + quad*8;
    bfr0[t] = *(const bf16x8*)b;
    bfr1[t] = *(const bf16x8*)(b + 32);
  }
  float local[4] = {0.f,0.f,0.f,0.f};
  int nw = (gridDim.x * blockDim.x) >> 6;
  f32x4 z = {0.f,0.f,0.f,0.f};
  for (int g = (blockIdx.x*blockDim.x + threadIdx.x) >> 6; g < nGroups; g += nw) {
    int m0 = g * 16;
    const float* hrow = h + (size_t)(m0 + row)*64 + quad*8;
    bf16x8 a0 = cvt8(hrow), a1 = cvt8(hrow + 32);
    f32x4 acc[8];
    #pragma unroll
    for (int t=0;t<8;t++) {
      acc[t] = MFMA16(a0, bfr0[t], z);
      acc[t] = MFMA16(a1, bfr1[t], acc[t]);
    }
    #pragma unroll
    for (int t=0;t<4;t++) {
      int d = t*16 + row;
      if (d < G) {
        float gb = gm_b[d], fb = fm_b[d];
        #pragma unroll
        for (int r=0;r<4;r++) {
          float gv = acc[t][r]   + gb;
          float hv = acc[4+t][r] + fb;
          local[t] += sigf(gv) * hv;
        }
      }
    }
  }
  #pragma unroll
  for (int t=0;t<4;t++) {
    float v = local[t];
    v += __shfl_xor(v, 16);
    v += __shfl_xor(v, 32);
    local[t] = v;
  }
  __shared__ float red[4][4][16];
  if (quad == 0)
    #pragma unroll
    for (int t=0;t<4;t++) red[wlocal][t][row] = local[t];
  __syncthreads();
  if (threadIdx.x < 64) {
    int d = threadIdx.x;
    if (d < G) {
      float v = red[0][d>>4][d&15] + red[1][d>>4][d&15] + red[2][d>>4][d&15] + red[3][d>>4][d&15];
      unsafeAtomicAdd(out + d, v);
    }
  }
}

extern "C" void kernel_launch(void* const* d_in, const int* in_sizes, int n_in,
                              void* d_out, int out_size, void* d_ws, size_t ws_size,
                              hipStream_t stream) {
  const float* x         = (const float*)d_in[0];
  const float* edge_attr = (const float*)d_in[1];
  const int*   edge_index= (const int*)  d_in[2];
  const float* fe_w1     = (const float*)d_in[3];
  const float* fe_b1     = (const float*)d_in[4];
  const float* fe_w2     = (const float*)d_in[5];
  const float* fe_b2     = (const float*)d_in[6];
  const float* lstm_wih  = (const float*)d_in[7];
  const float* lstm_whh  = (const float*)d_in[8];
  const float* lstm_bih  = (const float*)d_in[9];
  const float* lstm_bhh  = (const float*)d_in[10];
  const float* gm_w      = (const float*)d_in[11];
  const float* gm_b      = (const float*)d_in[12];
  const float* fm_w      = (const float*)d_in[13];
  const float* fm_b      = (const float*)d_in[14];
  float* out = (float*)d_out;

  const int N  = in_sizes[0] / 64;
  const int E  = in_sizes[1] / 32;
  const int P_ = in_sizes[3] / (64*160);
  const int G  = in_sizes[11] / 64;
  const int nGroups = N / 16;

  // ---- workspace layout (float units) ----
  float* f = (float*)d_ws;
  size_t o = 0;
  float* hA  = f + o;  o += (size_t)N*64;
  float* hB  = f + o;  o += (size_t)N*64;
  float* cB  = f + o;  o += (size_t)N*64;
  float* sB  = f + o;  o += (size_t)N*64;
  float* wb  = f + o;  o += (size_t)P_*256;
  __bf16* U  = (__bf16*)(f + o);  o += (size_t)N*32;
  __bf16* V  = (__bf16*)(f + o);  o += (size_t)N*32;
  int* degi   = (int*)(f + o);    o += (size_t)N;     // degi+cursor adjacent: one memset
  int* cursor = (int*)(f + o);    o += (size_t)N;
  int* offs   = (int*)(f + o);    o += (size_t)N + 1;
  int* bsum   = (int*)(f + o);    o += 512;
  int* perm   = (int*)(f + o);    o += (size_t)E;
  int* srcS   = (int*)(f + o);    o += (size_t)E;
  __bf16* EA  = (__bf16*)(f + o); o += ((size_t)E + 64)*16;  // sorted edge_attr, bf16, padded
  __bf16* Wuv = (__bf16*)(f + o);
  __bf16* Wc  = Wuv + (size_t)P_*128*64;
  __bf16* Wih = Wc  + (size_t)P_*64*32;
  __bf16* Mw  = Wih + (size_t)P_*256*64;
  __bf16* Rw  = Mw  + (size_t)P_*256*64;

  hipMemsetAsync(out, 0, (size_t)out_size*sizeof(float), stream);
  hipMemsetAsync(degi, 0, (size_t)2*N*sizeof(int), stream);  // degi + cursor

  // fused weight prep
  {
    int tot = P_*256*64 + P_*128*64 + P_*64*32 + P_*256*64 + 128*64;
    k_prep_all<<<(tot+255)/256, 256, 0, stream>>>(lstm_whh, fe_w2, fe_b2, fe_w1, lstm_wih,
                                                  gm_w, fm_w, Mw, wb, Wuv, Wc, Wih, Rw, P_, G);
  }

  // CSR build + EA permute (once)
  int nb = (N + 255) / 256;
  k_hist<<<(E+255)/256, 256, 0, stream>>>(edge_index, degi, E);
  k_bsum<<<nb, 256, 0, stream>>>(degi, bsum, N);
  k_bscan<<<1, 512, 0, stream>>>(bsum, nb);
  k_offs<<<nb, 256, 0, stream>>>(degi, bsum, offs, N);
  k_scatter<<<(E+255)/256, 256, 0, stream>>>(edge_index, offs, cursor, perm, srcS, E);
  {
    int waves = (E + 15) / 16;
    k_permEA<<<(waves + 3) / 4, 256, 0, stream>>>(edge_attr, perm, EA, E);
  }

  int nodeBlocks = (nGroups + 3) / 4;
  int aggrBlocks = (N + 3) / 4;

  for (int i = 0; i < P_; i++) {
    const float* h_in = (i == 0) ? x : ((i & 1) ? hA : hB);
    float*       h_out = (i & 1) ? hB : hA;

    k_prep_uv<<<nodeBlocks, 256, 0, stream>>>(h_in, Wuv + (size_t)i*128*64, U, V, nGroups);
    k_aggr_f<<<aggrBlocks, 256, 0, stream>>>(offs, srcS, EA, Wc + (size_t)i*64*32,
                                             fe_b1 + i*64, U, V, sB, N);
    k_lstm<<<nodeBlocks, 256, 0, stream>>>(h_in, sB, offs,
                                           Wih + (size_t)i*256*64, Mw + (size_t)i*256*64,
                                           wb + i*256, lstm_bih + i*256, lstm_bhh + i*256,
                                           h_out, cB, nGroups,
                                           /*has_c=*/(i > 0), /*write_c=*/(i < P_-1));
  }

  const float* h_fin = (P_ & 1) ? hA : hB;
  k_readout<<<512, 256, 0, stream>>>(h_fin, Rw, gm_b, fm_b, out, nGroups, G);
}

// Round 6
// 919.407 us; speedup vs baseline: 1.7942x; 1.1390x over previous
//
#include <hip/hip_runtime.h>
#include <hip/hip_bf16.h>
#include <math.h>

typedef __bf16  bf16x8 __attribute__((ext_vector_type(8)));
typedef float   f32x4  __attribute__((ext_vector_type(4)));

#define MFMA16(a,b,c) __builtin_amdgcn_mfma_f32_16x16x32_bf16((a),(b),(c),0,0,0)

__device__ __forceinline__ bf16x8 cvt8(const float* p) {
  const f32x4* q = (const f32x4*)p;
  f32x4 u = q[0], v = q[1];
  bf16x8 r;
  r[0]=(__bf16)u[0]; r[1]=(__bf16)u[1]; r[2]=(__bf16)u[2]; r[3]=(__bf16)u[3];
  r[4]=(__bf16)v[0]; r[5]=(__bf16)v[1]; r[6]=(__bf16)v[2]; r[7]=(__bf16)v[3];
  return r;
}

__device__ __forceinline__ float sigf(float x){ return 1.0f/(1.0f + __expf(-x)); }
__device__ __forceinline__ float tanhf_fast(float x){
  float ax = fabsf(x);
  float t = __expf(-2.f*ax);
  float r = (1.f - t)/(1.f + t);
  return copysignf(r, x);
}

// ---------------- fused weight prep ----------------
__global__ __launch_bounds__(256) void k_prep_all(const float* __restrict__ whh,
                                                  const float* __restrict__ w2,
                                                  const float* __restrict__ b2,
                                                  const float* __restrict__ fe_w1,
                                                  const float* __restrict__ lstm_wih,
                                                  const float* __restrict__ gm_w,
                                                  const float* __restrict__ fm_w,
                                                  __bf16* __restrict__ Mout,
                                                  float* __restrict__ wb,
                                                  __bf16* __restrict__ Wuv, __bf16* __restrict__ Wc,
                                                  __bf16* __restrict__ Wih, __bf16* __restrict__ R,
                                                  int P_, int G) {
  int idx = blockIdx.x*blockDim.x + threadIdx.x;
  int n0 = P_*256*64;
  if (idx < n0) {
    int c = idx & 63; int r = (idx >> 6) & 255; int i = idx >> 14;
    const float* wh  = whh + ((size_t)i*256 + r)*64;
    const float* w2i = w2  + (size_t)i*64*64;
    float acc = 0.f;
    #pragma unroll 8
    for (int j=0;j<64;j++) acc += wh[j] * w2i[j*64 + c];
    Mout[idx] = (__bf16)acc;
    if (c == 0) {
      const float* b2i = b2 + i*64;
      float a2 = 0.f;
      for (int j=0;j<64;j++) a2 += wh[j]*b2i[j];
      wb[i*256 + r] = a2;
    }
    return;
  }
  idx -= n0;
  int nA = P_*128*64, nB = P_*64*32, nC = P_*256*64, nD = 128*64;
  if (idx < nA) {
    int k = idx & 63, j = (idx >> 6) & 127, i = idx >> 13;
    Wuv[idx] = (__bf16)fe_w1[(size_t)i*10240 + (j&63)*160 + (j>>6)*64 + k];
    return;
  }
  idx -= nA;
  if (idx < nB) {
    int k = idx & 31, j = (idx >> 5) & 63, i = idx >> 11;
    Wc[idx] = (__bf16)fe_w1[(size_t)i*10240 + j*160 + 128 + k];
    return;
  }
  idx -= nB;
  if (idx < nC) { Wih[idx] = (__bf16)lstm_wih[idx]; return; }
  idx -= nC;
  if (idx < nD) {
    int k = idx & 63, j = idx >> 6;
    float v = 0.f;
    if (j < G) v = gm_w[j*64 + k];
    else if (j >= 64 && j < 64 + G) v = fm_w[(j-64)*64 + k];
    R[idx] = (__bf16)v;
  }
}

// ---------------- CSR construction (once per launch) ----------------
__global__ __launch_bounds__(256) void k_hist(const int* __restrict__ ei,
                                              int* __restrict__ degi, int E) {
  int e = blockIdx.x*blockDim.x + threadIdx.x;
  if (e < E) atomicAdd(&degi[ei[E + e]], 1);
}

__global__ __launch_bounds__(256) void k_bsum(const int* __restrict__ degi,
                                              int* __restrict__ bsum, int N) {
  __shared__ int sd[256];
  int idx = blockIdx.x*256 + threadIdx.x;
  sd[threadIdx.x] = (idx < N) ? degi[idx] : 0;
  __syncthreads();
  for (int s = 128; s > 0; s >>= 1) {
    if (threadIdx.x < s) sd[threadIdx.x] += sd[threadIdx.x + s];
    __syncthreads();
  }
  if (threadIdx.x == 0) bsum[blockIdx.x] = sd[0];
}

__global__ __launch_bounds__(512) void k_bscan(int* __restrict__ bsum, int nb) {
  __shared__ int s[512];
  int t = threadIdx.x;
  int v = (t < nb) ? bsum[t] : 0;
  s[t] = v;
  __syncthreads();
  #pragma unroll
  for (int off = 1; off < 512; off <<= 1) {
    int a = (t >= off) ? s[t - off] : 0;
    __syncthreads();
    s[t] += a;
    __syncthreads();
  }
  if (t < nb) bsum[t] = s[t] - v;
}

__global__ __launch_bounds__(256) void k_offs(const int* __restrict__ degi,
                                              const int* __restrict__ bsum,
                                              int* __restrict__ offs, int N) {
  __shared__ int sd[256];
  int idx = blockIdx.x*256 + threadIdx.x;
  int v = (idx < N) ? degi[idx] : 0;
  sd[threadIdx.x] = v;
  __syncthreads();
  #pragma unroll
  for (int sft = 1; sft < 256; sft <<= 1) {
    int add = (threadIdx.x >= sft) ? sd[threadIdx.x - sft] : 0;
    __syncthreads();
    sd[threadIdx.x] += add;
    __syncthreads();
  }
  if (idx <= N) offs[idx] = bsum[blockIdx.x] + sd[threadIdx.x] - v;
}

__global__ __launch_bounds__(256) void k_scatter(const int* __restrict__ ei,
                                                 const int* __restrict__ offs,
                                                 int* __restrict__ cursor,
                                                 int* __restrict__ perm,
                                                 int* __restrict__ dstS,
                                                 int* __restrict__ srcS, int E) {
  int e = blockIdx.x*blockDim.x + threadIdx.x;
  if (e >= E) return;
  int d = ei[E + e];
  int p = offs[d] + atomicAdd(&cursor[d], 1);
  perm[p] = e;
  dstS[p] = d;
  srcS[p] = ei[e];
}

// permute edge_attr into sorted order, bf16 (one-time)
__global__ __launch_bounds__(256) void k_permEA(const float* __restrict__ ea,
                                                const int* __restrict__ perm,
                                                __bf16* __restrict__ EA, int E) {
  int wv = (blockIdx.x*blockDim.x + threadIdx.x) >> 6;
  int lane = threadIdx.x & 63;
  int p0 = wv * 16;
  if (p0 >= E) return;
  int r = lane >> 2, cpart = lane & 3;
  int p = p0 + r;
  if (p >= E) return;
  int e = perm[p];
  bf16x8 v = cvt8(ea + (size_t)e*32 + cpart*8);
  *(bf16x8*)(EA + (size_t)p*32 + cpart*8) = v;
}

// ---------------- K1: U=h@W1a^T, V=h@W1b^T (bf16 out) ----------------
__global__ __launch_bounds__(256) void k_prep_uv(const float* __restrict__ h,
                                                 const __bf16* __restrict__ Wuv,
                                                 __bf16* __restrict__ U,
                                                 __bf16* __restrict__ V, int nGroups) {
  int wave = (blockIdx.x*blockDim.x + threadIdx.x) >> 6;
  if (wave >= nGroups) return;
  int lane = threadIdx.x & 63, row = lane & 15, quad = lane >> 4;
  int m0 = wave * 16;
  const float* arow = h + (size_t)(m0 + row)*64 + quad*8;
  bf16x8 a0 = cvt8(arow);
  bf16x8 a1 = cvt8(arow + 32);
  f32x4 z = {0.f,0.f,0.f,0.f};
  f32x4 acc[8];
  #pragma unroll
  for (int t=0;t<8;t++) acc[t] = z;
  #pragma unroll
  for (int t=0;t<8;t++) {
    const __bf16* b = Wuv + (t*16 + row)*64 + quad*8;
    acc[t] = MFMA16(a0, *(const bf16x8*)b,        acc[t]);
    acc[t] = MFMA16(a1, *(const bf16x8*)(b + 32), acc[t]);
  }
  #pragma unroll
  for (int t=0;t<8;t++) {
    __bf16* dst = (t < 4) ? U : V;
    int f = (t & 3)*16 + row;
    #pragma unroll
    for (int r=0;r<4;r++)
      dst[(size_t)(m0 + quad*4 + r)*64 + f] = (__bf16)acc[t][r];
  }
}

// ---------------- edge-centric aggregation: 64 sorted edges/wave, ballot runs ----------------
__global__ __launch_bounds__(256) void k_aggr_e(const int* __restrict__ dstS,
                                                const int* __restrict__ srcS,
                                                const __bf16* __restrict__ EA,
                                                const __bf16* __restrict__ Wc,
                                                const float* __restrict__ b1,
                                                const __bf16* __restrict__ U,
                                                const __bf16* __restrict__ V,
                                                float* __restrict__ sacc, int E) {
  __shared__ float ldsb[4][16*68];   // stride 68: conflict-free (2 lanes/bank)
  int wib = threadIdx.x >> 6;
  int lane = threadIdx.x & 63, row = lane & 15, quad = lane >> 4;

  int e0 = (blockIdx.x*4 + wib) * 64;
  if (e0 >= E) return;

  // coalesced per-lane edge metadata
  int eidx = min(e0 + lane, E - 1);
  int dv = dstS[eidx];
  int sv = srcS[eidx];

  // run-boundary mask (computed once, lives in SGPRs)
  int prevd = __shfl_up(dv, 1);
  unsigned long long bmask = __ballot((lane == 0) || (dv != prevd));

  // all 4 EA fragments up front (EA padded past E)
  bf16x8 a[4];
  #pragma unroll
  for (int st=0;st<4;st++)
    a[st] = *(const bf16x8*)(EA + (size_t)(e0 + st*16 + row)*32 + quad*8);

  bf16x8 bfr[4]; float bias[4];
  #pragma unroll
  for (int t=0;t<4;t++) {
    bfr[t] = *(const bf16x8*)(Wc + (t*16 + row)*32 + quad*8);
    bias[t] = b1[t*16 + row];
  }

  // uu/vv double-buffered prefetch (scalar-base loads via readlane)
  __bf16 uu[2][16], vv[2][16];
  #pragma unroll
  for (int r=0;r<16;r++) {
    int s = __builtin_amdgcn_readlane(sv, r);
    int d = __builtin_amdgcn_readlane(dv, r);
    vv[0][r] = V[(size_t)s*64 + lane];
    uu[0][r] = U[(size_t)d*64 + lane];
  }

  float acc = 0.f;
  int dcur = __builtin_amdgcn_readlane(dv, 0);
  float* L = &ldsb[wib][0];
  f32x4 z = {0.f,0.f,0.f,0.f};

  #pragma unroll
  for (int st=0; st<4; st++) {
    const int cur = st & 1, nxt = cur ^ 1;
    // EW subtile via MFMA + LDS transpose
    #pragma unroll
    for (int t=0;t<4;t++) {
      f32x4 c4 = MFMA16(a[st], bfr[t], z);
      #pragma unroll
      for (int r=0;r<4;r++)
        L[(quad*4 + r)*68 + t*16 + row] = c4[r] + bias[t];
    }
    // prefetch next subtile's uu/vv while LDS/MFMA results settle
    if (st < 3) {
      #pragma unroll
      for (int r=0;r<16;r++) {
        int s = __builtin_amdgcn_readlane(sv, (st+1)*16 + r);
        int d = __builtin_amdgcn_readlane(dv, (st+1)*16 + r);
        vv[nxt][r] = V[(size_t)s*64 + lane];
        uu[nxt][r] = U[(size_t)d*64 + lane];
      }
    }
    // accumulate with scalar-mask run flushes
    #pragma unroll
    for (int r=0;r<16;r++) {
      const int idx = st*16 + r;
      if (idx > 0 && (bmask & (1ull << idx))) {
        unsafeAtomicAdd(&sacc[(size_t)dcur*64 + lane], acc);
        acc = 0.f;
        dcur = __builtin_amdgcn_readlane(dv, idx);
      }
      if (e0 + idx < E) {
        float t2 = (float)uu[cur][r] + (float)vv[cur][r] + L[r*68 + lane];
        acc += t2 > 0.f ? t2 : 0.f;
      }
    }
  }
  unsafeAtomicAdd(&sacc[(size_t)dcur*64 + lane], acc);
}

// ---------------- K4: gates + LSTM update (all loads hoisted) ----------------
__global__ __launch_bounds__(256) void k_lstm(const float* __restrict__ h_in,
                                              const float* __restrict__ sacc,
                                              const int* __restrict__ offs,
                                              const __bf16* __restrict__ Wih,
                                              const __bf16* __restrict__ Mw,
                                              const float* __restrict__ wb,
                                              const float* __restrict__ bih,
                                              const float* __restrict__ bhh,
                                              float* __restrict__ h_out,
                                              float* __restrict__ c, int nGroups,
                                              int has_c, int write_c) {
  int wave = (blockIdx.x*blockDim.x + threadIdx.x) >> 6;
  if (wave >= nGroups) return;
  int lane = threadIdx.x & 63, row = lane & 15, quad = lane >> 4;
  int m0 = wave * 16;

  float wbv[4][4], bsv[4][4];
  #pragma unroll
  for (int g=0; g<4; g++)
    #pragma unroll
    for (int t=0; t<4; t++) {
      int dcol = g*64 + t*16 + row;
      wbv[g][t] = wb[dcol];
      bsv[g][t] = bih[dcol] + bhh[dcol];
    }
  float dgv[4];
  #pragma unroll
  for (int r=0;r<4;r++) {
    int node = m0 + quad*4 + r;
    dgv[r] = (float)(offs[node+1] - offs[node]);
  }
  float cold[4][4];
  if (has_c) {
    #pragma unroll
    for (int t=0;t<4;t++)
      #pragma unroll
      for (int r=0;r<4;r++)
        cold[t][r] = c[(size_t)(m0 + quad*4 + r)*64 + t*16 + row];
  } else {
    #pragma unroll
    for (int t=0;t<4;t++)
      #pragma unroll
      for (int r=0;r<4;r++) cold[t][r] = 0.f;
  }

  const float* hrow = h_in + (size_t)(m0 + row)*64 + quad*8;
  const float* srow = sacc + (size_t)(m0 + row)*64 + quad*8;
  bf16x8 ah0 = cvt8(hrow), ah1 = cvt8(hrow + 32);
  bf16x8 as0 = cvt8(srow), as1 = cvt8(srow + 32);
  f32x4 z = {0.f,0.f,0.f,0.f};
  f32x4 acc[16];
  #pragma unroll
  for (int t=0;t<16;t++) acc[t] = z;
  #pragma unroll
  for (int t=0;t<16;t++) {
    const __bf16* bw = Wih + (t*16 + row)*64 + quad*8;
    const __bf16* bm = Mw  + (t*16 + row)*64 + quad*8;
    acc[t] = MFMA16(ah0, *(const bf16x8*)bw,        acc[t]);
    acc[t] = MFMA16(ah1, *(const bf16x8*)(bw + 32), acc[t]);
    acc[t] = MFMA16(as0, *(const bf16x8*)bm,        acc[t]);
    acc[t] = MFMA16(as1, *(const bf16x8*)(bm + 32), acc[t]);
  }
  #pragma unroll
  for (int r=0;r<4;r++) {
    int node = m0 + quad*4 + r;
    float dg = dgv[r];
    #pragma unroll
    for (int t=0;t<4;t++) {
      float gi = acc[t][r]     + dg*wbv[0][t] + bsv[0][t];
      float gf = acc[4+t][r]   + dg*wbv[1][t] + bsv[1][t];
      float gg = acc[8+t][r]   + dg*wbv[2][t] + bsv[2][t];
      float go = acc[12+t][r]  + dg*wbv[3][t] + bsv[3][t];
      size_t ci = (size_t)node*64 + t*16 + row;
      float cn = sigf(gf)*cold[t][r] + sigf(gi)*tanhf_fast(gg);
      float hn = sigf(go)*tanhf_fast(cn);
      if (write_c) c[ci] = cn;
      h_out[ci] = hn;
    }
  }
}

// ---------------- readout ----------------
__global__ __launch_bounds__(256) void k_readout(const float* __restrict__ h,
                                                 const __bf16* __restrict__ R,
                                                 const float* __restrict__ gm_b,
                                                 const float* __restrict__ fm_b,
                                                 float* __restrict__ out,
                                                 int nGroups, int G) {
  int lane = threadIdx.x & 63, row = lane & 15, quad = lane >> 4;
  int wlocal = threadIdx.x >> 6;
  bf16x8 bfr0[8], bfr1[8];
  #pragma unroll
  for (int t=0;t<8;t++) {
    const __bf16* b = R + (t*16 + row)*64 + quad*8;
    bfr0[t] = *(const bf16x8*)b;
    bfr1[t] = *(const bf16x8*)(b + 32);
  }
  float local[4] = {0.f,0.f,0.f,0.f};
  int nw = (gridDim.x * blockDim.x) >> 6;
  f32x4 z = {0.f,0.f,0.f,0.f};
  for (int g = (blockIdx.x*blockDim.x + threadIdx.x) >> 6; g < nGroups; g += nw) {
    int m0 = g * 16;
    const float* hrow = h + (size_t)(m0 + row)*64 + quad*8;
    bf16x8 a0 = cvt8(hrow), a1 = cvt8(hrow + 32);
    f32x4 acc[8];
    #pragma unroll
    for (int t=0;t<8;t++) {
      acc[t] = MFMA16(a0, bfr0[t], z);
      acc[t] = MFMA16(a1, bfr1[t], acc[t]);
    }
    #pragma unroll
    for (int t=0;t<4;t++) {
      int d = t*16 + row;
      if (d < G) {
        float gb = gm_b[d], fb = fm_b[d];
        #pragma unroll
        for (int r=0;r<4;r++) {
          float gv = acc[t][r]   + gb;
          float hv = acc[4+t][r] + fb;
          local[t] += sigf(gv) * hv;
        }
      }
    }
  }
  #pragma unroll
  for (int t=0;t<4;t++) {
    float v = local[t];
    v += __shfl_xor(v, 16);
    v += __shfl_xor(v, 32);
    local[t] = v;
  }
  __shared__ float red[4][4][16];
  if (quad == 0)
    #pragma unroll
    for (int t=0;t<4;t++) red[wlocal][t][row] = local[t];
  __syncthreads();
  if (threadIdx.x < 64) {
    int d = threadIdx.x;
    if (d < G) {
      float v = red[0][d>>4][d&15] + red[1][d>>4][d&15] + red[2][d>>4][d&15] + red[3][d>>4][d&15];
      unsafeAtomicAdd(out + d, v);
    }
  }
}

extern "C" void kernel_launch(void* const* d_in, const int* in_sizes, int n_in,
                              void* d_out, int out_size, void* d_ws, size_t ws_size,
                              hipStream_t stream) {
  const float* x         = (const float*)d_in[0];
  const float* edge_attr = (const float*)d_in[1];
  const int*   edge_index= (const int*)  d_in[2];
  const float* fe_w1     = (const float*)d_in[3];
  const float* fe_b1     = (const float*)d_in[4];
  const float* fe_w2     = (const float*)d_in[5];
  const float* fe_b2     = (const float*)d_in[6];
  const float* lstm_wih  = (const float*)d_in[7];
  const float* lstm_whh  = (const float*)d_in[8];
  const float* lstm_bih  = (const float*)d_in[9];
  const float* lstm_bhh  = (const float*)d_in[10];
  const float* gm_w      = (const float*)d_in[11];
  const float* gm_b      = (const float*)d_in[12];
  const float* fm_w      = (const float*)d_in[13];
  const float* fm_b      = (const float*)d_in[14];
  float* out = (float*)d_out;

  const int N  = in_sizes[0] / 64;
  const int E  = in_sizes[1] / 32;
  const int P_ = in_sizes[3] / (64*160);
  const int G  = in_sizes[11] / 64;
  const int nGroups = N / 16;

  // ---- workspace layout (float units) ----
  float* f = (float*)d_ws;
  size_t o = 0;
  float* hA  = f + o;  o += (size_t)N*64;
  float* hB  = f + o;  o += (size_t)N*64;
  float* cB  = f + o;  o += (size_t)N*64;
  float* sB  = f + o;  o += (size_t)N*64;
  float* wb  = f + o;  o += (size_t)P_*256;
  __bf16* U  = (__bf16*)(f + o);  o += (size_t)N*32;
  __bf16* V  = (__bf16*)(f + o);  o += (size_t)N*32;
  int* degi   = (int*)(f + o);    o += (size_t)N;
  int* cursor = (int*)(f + o);    o += (size_t)N;
  int* offs   = (int*)(f + o);    o += (size_t)N + 1;
  int* bsum   = (int*)(f + o);    o += 512;
  int* perm   = (int*)(f + o);    o += (size_t)E;
  int* dstS   = (int*)(f + o);    o += (size_t)E;
  int* srcS   = (int*)(f + o);    o += (size_t)E;
  __bf16* EA  = (__bf16*)(f + o); o += ((size_t)E + 64)*16;  // sorted edge_attr, bf16, padded
  __bf16* Wuv = (__bf16*)(f + o);
  __bf16* Wc  = Wuv + (size_t)P_*128*64;
  __bf16* Wih = Wc  + (size_t)P_*64*32;
  __bf16* Mw  = Wih + (size_t)P_*256*64;
  __bf16* Rw  = Mw  + (size_t)P_*256*64;

  hipMemsetAsync(out, 0, (size_t)out_size*sizeof(float), stream);
  hipMemsetAsync(degi, 0, (size_t)2*N*sizeof(int), stream);  // degi + cursor

  // fused weight prep
  {
    int tot = P_*256*64 + P_*128*64 + P_*64*32 + P_*256*64 + 128*64;
    k_prep_all<<<(tot+255)/256, 256, 0, stream>>>(lstm_whh, fe_w2, fe_b2, fe_w1, lstm_wih,
                                                  gm_w, fm_w, Mw, wb, Wuv, Wc, Wih, Rw, P_, G);
  }

  // CSR build + EA permute (once)
  int nb = (N + 255) / 256;
  k_hist<<<(E+255)/256, 256, 0, stream>>>(edge_index, degi, E);
  k_bsum<<<nb, 256, 0, stream>>>(degi, bsum, N);
  k_bscan<<<1, 512, 0, stream>>>(bsum, nb);
  k_offs<<<nb, 256, 0, stream>>>(degi, bsum, offs, N);
  k_scatter<<<(E+255)/256, 256, 0, stream>>>(edge_index, offs, cursor, perm, dstS, srcS, E);
  {
    int waves = (E + 15) / 16;
    k_permEA<<<(waves + 3) / 4, 256, 0, stream>>>(edge_attr, perm, EA, E);
  }

  int nodeBlocks = (nGroups + 3) / 4;
  int chunkBlocks = ((E + 63)/64 + 3) / 4;

  for (int i = 0; i < P_; i++) {
    const float* h_in = (i == 0) ? x : ((i & 1) ? hA : hB);
    float*       h_out = (i & 1) ? hB : hA;

    k_prep_uv<<<nodeBlocks, 256, 0, stream>>>(h_in, Wuv + (size_t)i*128*64, U, V, nGroups);
    hipMemsetAsync(sB, 0, (size_t)N*64*sizeof(float), stream);
    k_aggr_e<<<chunkBlocks, 256, 0, stream>>>(dstS, srcS, EA, Wc + (size_t)i*64*32,
                                              fe_b1 + i*64, U, V, sB, E);
    k_lstm<<<nodeBlocks, 256, 0, stream>>>(h_in, sB, offs,
                                           Wih + (size_t)i*256*64, Mw + (size_t)i*256*64,
                                           wb + i*256, lstm_bih + i*256, lstm_bhh + i*256,
                                           h_out, cB, nGroups,
                                           /*has_c=*/(i > 0), /*write_c=*/(i < P_-1));
  }

  const float* h_fin = (P_ & 1) ? hA : hB;
  k_readout<<<512, 256, 0, stream>>>(h_fin, Rw, gm_b, fm_b, out, nGroups, G);
}